// Round 2
// baseline (449.739 us; speedup 1.0000x reference)
//
#include <hip/hip_runtime.h>

// ---------------- constants ----------------
#define Bk 32      // batch
#define Nn 128     // nodes
#define Cc 128     // in channels
#define HE 64      // edge hidden
#define BN_EPS 1e-5f

// workspace offsets (floats)
#define OFF_U    ((size_t)0)         // 262144
#define OFF_V    ((size_t)262144)    // 262144
#define OFF_S    ((size_t)524288)    // 524288
#define OFF_AP   ((size_t)1048576)   // 524288
#define OFF_RS   ((size_t)1572864)   // 4096
#define OFF_AN   ((size_t)1576960)   // 524288
#define OFF_D    ((size_t)2101248)   // 8192
#define OFF_L    ((size_t)2109440)   // 1048576 (2 rels x 32 x 128 x 128)
#define OFF_H0   ((size_t)3158016)   // 262144
#define OFF_H1   ((size_t)3420160)   // 1048576
#define OFF_H2   ((size_t)4468736)   // 2097152
#define OFF_XCAT ((size_t)6565888)   // 6291456 (max layer: 4096 x 1536)
#define OFF_POOL ((size_t)12857344)  // 16384
// total 12873728 floats = 51.5 MB

// ---------------- edge MLP: u = x@W1[:C] + b1, v = x@W1[C:] ----------------
__global__ __launch_bounds__(128) void edge_uv(const float* __restrict__ x,
                                               const float* __restrict__ eW1,
                                               const float* __restrict__ eb1,
                                               float* __restrict__ u, float* __restrict__ v) {
    int bn = blockIdx.x;          // 0..4095
    int tid = threadIdx.x;        // 128
    __shared__ float xs[Cc];
    xs[tid] = x[(size_t)bn * Cc + tid];
    __syncthreads();
    int h = tid & 63;
    int which = tid >> 6;         // 0 -> u, 1 -> v
    const float* W = eW1 + (size_t)which * Cc * HE + h;
    float acc = 0.f;
#pragma unroll 8
    for (int c = 0; c < Cc; ++c) acc += xs[c] * W[(size_t)c * HE];
    if (which == 0) u[(size_t)bn * HE + h] = acc + eb1[h];
    else            v[(size_t)bn * HE + h] = acc;
}

// ---------------- edge scores s[b,i,j] ----------------
__global__ __launch_bounds__(256) void edge_score(const float* __restrict__ u,
                                                  const float* __restrict__ v,
                                                  const float* __restrict__ eW2,
                                                  const float* __restrict__ eb2,
                                                  float* __restrict__ s) {
    __shared__ float us[16][68], vs[16][68], w2[HE];
    int b = blockIdx.z;
    int i0 = blockIdx.y * 16, j0 = blockIdx.x * 16;
    int tid = threadIdx.x;
    int r = tid >> 4, c4 = (tid & 15) * 4;
    {
        const float4 uv = *(const float4*)(u + ((size_t)(b * Nn + i0 + r)) * HE + c4);
        us[r][c4] = uv.x; us[r][c4 + 1] = uv.y; us[r][c4 + 2] = uv.z; us[r][c4 + 3] = uv.w;
        const float4 vv = *(const float4*)(v + ((size_t)(b * Nn + j0 + r)) * HE + c4);
        vs[r][c4] = vv.x; vs[r][c4 + 1] = vv.y; vs[r][c4 + 2] = vv.z; vs[r][c4 + 3] = vv.w;
    }
    if (tid < HE) w2[tid] = eW2[tid];
    __syncthreads();
    int il = tid >> 4, jl = tid & 15;
    float acc = 0.f;
#pragma unroll
    for (int h = 0; h < HE; ++h) {
        float t = us[il][h] + vs[jl][h];
        acc += fmaxf(t, 0.f) * w2[h];
    }
    s[((size_t)(b * Nn + i0 + il)) * Nn + j0 + jl] = acc + eb2[0];
}

// ---------------- A_pred (tri-masked exp) + row sums ----------------
__global__ __launch_bounds__(128) void edge_ap(const float* __restrict__ s,
                                               const float* __restrict__ mask,
                                               float* __restrict__ ap, float* __restrict__ rs) {
    int bi = blockIdx.x;               // b*128+i
    int b = bi >> 7, i = bi & 127;
    int j = threadIdx.x;
    float mi = mask[b * Nn + i];
    float mj = mask[b * Nn + j];
    float val = 0.f;
    if (j > i && mi != 0.f && mj != 0.f) {
        float sij = s[((size_t)bi) * Nn + j];
        float sji = s[((size_t)(b * Nn + j)) * Nn + i];
        val = expf(fminf(0.5f * (sij + sji), 80.f)) * (mi * mj);
    }
    ap[((size_t)bi) * Nn + j] = val;
    __shared__ float red[128];
    red[j] = val;
    __syncthreads();
    for (int ofs = 64; ofs > 0; ofs >>= 1) {
        if (j < ofs) red[j] += red[j + ofs];
        __syncthreads();
    }
    if (j == 0) {
        float r = red[0];
        rs[bi] = (r == 0.f) ? 1.f : r;
    }
}

// ---------------- An = ap/rs + (ap/rs)^T ----------------
__global__ __launch_bounds__(128) void edge_an(const float* __restrict__ ap,
                                               const float* __restrict__ rs,
                                               float* __restrict__ An) {
    int bi = blockIdx.x;
    int b = bi >> 7, i = bi & 127;
    int j = threadIdx.x;
    float a_ij = ap[((size_t)bi) * Nn + j];
    float a_ji = ap[((size_t)(b * Nn + j)) * Nn + i];
    An[((size_t)bi) * Nn + j] = a_ij / rs[bi] + a_ji / rs[b * Nn + j];
}

// ---------------- degrees D[rel,b,j] = (colsum + 1e-5)^-1/2 ----------------
__global__ __launch_bounds__(128) void degrees(const float* __restrict__ A,
                                               const float* __restrict__ An,
                                               float* __restrict__ D) {
    int b = blockIdx.x >> 1, rel = blockIdx.x & 1;
    int j = threadIdx.x;
    const float* Ar = (rel ? An : A) + (size_t)b * Nn * Nn;
    float sum = 0.f;
    for (int i = 0; i < Nn; ++i) sum += Ar[(size_t)i * Nn + j];
    D[(size_t)(rel * Bk + b) * Nn + j] = rsqrtf(sum + 1e-5f);
}

// ---------------- L[rel,b,i,j] = D_i * Ar_ij * D_j ----------------
__global__ __launch_bounds__(256) void buildL(const float* __restrict__ A,
                                              const float* __restrict__ An,
                                              const float* __restrict__ D,
                                              float* __restrict__ L) {
    int idx = blockIdx.x * 256 + threadIdx.x;   // < 2*32*128*128 = 1048576
    int j = idx & 127, i = (idx >> 7) & 127, b = (idx >> 14) & 31, rel = idx >> 19;
    const float* Ar = rel ? An : A;
    float a = Ar[((size_t)(b * Nn + i)) * Nn + j];
    L[idx] = D[(size_t)(rel * Bk + b) * Nn + i] * a * D[(size_t)(rel * Bk + b) * Nn + j];
}

// ---------------- copy T0 slices into Xcat ----------------
__global__ __launch_bounds__(256) void copy_t0(const float* __restrict__ xh,
                                               float* __restrict__ Xcat, int fin) {
    int t = blockIdx.x * 256 + threadIdx.x;
    int e = t * 4;
    int total = 2 * 4096 * fin;
    if (e >= total) return;
    int rel = e / (4096 * fin);
    int r2 = e - rel * 4096 * fin;
    int bn = r2 / fin;
    int c = r2 - bn * fin;
    float4 val = *(const float4*)(xh + (size_t)bn * fin + c);
    *(float4*)(Xcat + (size_t)bn * 6 * fin + rel * 3 * fin + c) = val;
}

// ---------------- batched Cheb matmul: C = alpha * L[rel,b] @ Xin (- Sub) ----------------
__global__ __launch_bounds__(256) void cheb_mm(const float* __restrict__ L,
                                               const float* __restrict__ Xin, int ld_in,
                                               int in_rel_ofs, int in_ofs,
                                               const float* __restrict__ Sub, int ld_sub,
                                               float alpha,
                                               float* __restrict__ Cout, int ld_out,
                                               int out_rel_ofs, int out_ofs) {
    int z = blockIdx.z;
    int b = z & 31, rel = z >> 5;
    const float* Lb = L + ((size_t)(rel * Bk + b)) * Nn * Nn;
    const float* Xb = Xin + (size_t)b * Nn * ld_in + rel * in_rel_ofs + in_ofs;
    const float* Sb = Sub ? (Sub + (size_t)b * Nn * ld_sub) : nullptr;
    float* Cb = Cout + (size_t)b * Nn * ld_out + rel * out_rel_ofs + out_ofs;

    int row0 = blockIdx.y * 64, col0 = blockIdx.x * 64;
    __shared__ float As[16][65];
    __shared__ float Bs[16][64];
    int tid = threadIdx.x;
    int ar = tid >> 2, ak = (tid & 3) << 2;
    int bk = tid >> 4, bc = (tid & 15) << 2;
    int tr = (tid >> 4) << 2, tc = (tid & 15) << 2;
    float acc[4][4] = {};
    for (int k0 = 0; k0 < Nn; k0 += 16) {
        float4 av = *(const float4*)(Lb + (size_t)(row0 + ar) * Nn + k0 + ak);
        As[ak][ar] = av.x; As[ak + 1][ar] = av.y; As[ak + 2][ar] = av.z; As[ak + 3][ar] = av.w;
        float4 bv = *(const float4*)(Xb + (size_t)(k0 + bk) * ld_in + col0 + bc);
        *(float4*)&Bs[bk][bc] = bv;
        __syncthreads();
#pragma unroll
        for (int k = 0; k < 16; ++k) {
            float a[4], bb[4];
#pragma unroll
            for (int q = 0; q < 4; ++q) { a[q] = As[k][tr + q]; bb[q] = Bs[k][tc + q]; }
#pragma unroll
            for (int ii = 0; ii < 4; ++ii)
#pragma unroll
                for (int jj = 0; jj < 4; ++jj) acc[ii][jj] = fmaf(a[ii], bb[jj], acc[ii][jj]);
        }
        __syncthreads();
    }
#pragma unroll
    for (int ii = 0; ii < 4; ++ii) {
#pragma unroll
        for (int jj = 0; jj < 4; ++jj) {
            int row = row0 + tr + ii, col = col0 + tc + jj;
            float vout = alpha * acc[ii][jj];
            if (Sb) vout -= Sb[(size_t)row * ld_sub + col];
            Cb[(size_t)row * ld_out + col] = vout;
        }
    }
}

// ---------------- fc GEMM + bias + mask + BN(eval) + relu ----------------
__global__ __launch_bounds__(256) void fc_gemm(const float* __restrict__ A,
                                               const float* __restrict__ W,
                                               const float* __restrict__ bias,
                                               const float* __restrict__ mask,
                                               const float* __restrict__ bnG,
                                               const float* __restrict__ bnB,
                                               const float* __restrict__ bnM,
                                               const float* __restrict__ bnV,
                                               float* __restrict__ out, int Kd, int F) {
    __shared__ float As[16][65];
    __shared__ float Bs[16][64];
    int tid = threadIdx.x;
    int row0 = blockIdx.y * 64, col0 = blockIdx.x * 64;
    int ar = tid >> 2, ak = (tid & 3) << 2;
    int bk = tid >> 4, bc = (tid & 15) << 2;
    int tr = (tid >> 4) << 2, tc = (tid & 15) << 2;
    float acc[4][4] = {};
    for (int k0 = 0; k0 < Kd; k0 += 16) {
        float4 av = *(const float4*)(A + (size_t)(row0 + ar) * Kd + k0 + ak);
        As[ak][ar] = av.x; As[ak + 1][ar] = av.y; As[ak + 2][ar] = av.z; As[ak + 3][ar] = av.w;
        float4 wv = *(const float4*)(W + (size_t)(k0 + bk) * F + col0 + bc);
        *(float4*)&Bs[bk][bc] = wv;
        __syncthreads();
#pragma unroll
        for (int k = 0; k < 16; ++k) {
            float a[4], bb[4];
#pragma unroll
            for (int q = 0; q < 4; ++q) { a[q] = As[k][tr + q]; bb[q] = Bs[k][tc + q]; }
#pragma unroll
            for (int ii = 0; ii < 4; ++ii)
#pragma unroll
                for (int jj = 0; jj < 4; ++jj) acc[ii][jj] = fmaf(a[ii], bb[jj], acc[ii][jj]);
        }
        __syncthreads();
    }
#pragma unroll
    for (int ii = 0; ii < 4; ++ii) {
        int row = row0 + tr + ii;
        float mrow = mask[row];
#pragma unroll
        for (int jj = 0; jj < 4; ++jj) {
            int col = col0 + tc + jj;
            float h = acc[ii][jj] + bias[col];
            h *= mrow;
            h = (h - bnM[col]) * rsqrtf(bnV[col] + BN_EPS) * bnG[col] + bnB[col];
            out[(size_t)row * F + col] = fmaxf(h, 0.f);
        }
    }
}

// ---------------- max pool over nodes ----------------
__global__ __launch_bounds__(512) void pool_max(const float* __restrict__ h2, float* __restrict__ pooled) {
    int b = blockIdx.x;
    int f = threadIdx.x;   // 512
    const float* p = h2 + (size_t)b * Nn * 512 + f;
    float m = p[0];
    for (int n = 1; n < Nn; ++n) m = fmaxf(m, p[(size_t)n * 512]);
    pooled[(size_t)b * 512 + f] = m;
}

// ---------------- classifier: (pooled@fW1+fb1)@fW2+fb2 ----------------
__global__ __launch_bounds__(256) void classifier(const float* __restrict__ pooled,
                                                  const float* __restrict__ fW1,
                                                  const float* __restrict__ fb1,
                                                  const float* __restrict__ fW2,
                                                  const float* __restrict__ fb2,
                                                  float* __restrict__ out) {
    int b = blockIdx.x;
    int tid = threadIdx.x;    // 256
    __shared__ float ps[512], hs[256];
    ps[tid] = pooled[(size_t)b * 512 + tid];
    ps[tid + 256] = pooled[(size_t)b * 512 + 256 + tid];
    __syncthreads();
    float acc = fb1[tid];
    for (int c = 0; c < 512; ++c) acc += ps[c] * fW1[(size_t)c * 256 + tid];
    hs[tid] = acc;
    __syncthreads();
    if (tid < 10) {
        float o = fb2[tid];
        for (int h = 0; h < 256; ++h) o += hs[h] * fW2[(size_t)h * 10 + tid];
        out[(size_t)b * 10 + tid] = o;
    }
}

extern "C" void kernel_launch(void* const* d_in, const int* in_sizes, int n_in,
                              void* d_out, int out_size, void* d_ws, size_t ws_size,
                              hipStream_t stream) {
    const float* x    = (const float*)d_in[0];
    const float* Ain  = (const float*)d_in[1];
    const float* mask = (const float*)d_in[2];
    const float* eW1  = (const float*)d_in[3];
    const float* eb1  = (const float*)d_in[4];
    const float* eW2  = (const float*)d_in[5];
    const float* eb2  = (const float*)d_in[6];
    const float* fW1  = (const float*)d_in[25];
    const float* fb1  = (const float*)d_in[26];
    const float* fW2  = (const float*)d_in[27];
    const float* fb2  = (const float*)d_in[28];

    float* ws = (float*)d_ws;
    float* u  = ws + OFF_U;
    float* v  = ws + OFF_V;
    float* s  = ws + OFF_S;
    float* ap = ws + OFF_AP;
    float* rs = ws + OFF_RS;
    float* An = ws + OFF_AN;
    float* D  = ws + OFF_D;
    float* Lw = ws + OFF_L;
    float* h0 = ws + OFF_H0;
    float* h1 = ws + OFF_H1;
    float* h2 = ws + OFF_H2;
    float* Xc = ws + OFF_XCAT;
    float* pl = ws + OFF_POOL;

    // edge adjacency
    edge_uv<<<Bk * Nn, 128, 0, stream>>>(x, eW1, eb1, u, v);
    edge_score<<<dim3(8, 8, Bk), 256, 0, stream>>>(u, v, eW2, eb2, s);
    edge_ap<<<Bk * Nn, 128, 0, stream>>>(s, mask, ap, rs);
    edge_an<<<Bk * Nn, 128, 0, stream>>>(ap, rs, An);

    // Laplacians (shared across all 3 layers)
    degrees<<<Bk * 2, 128, 0, stream>>>(Ain, An, D);
    buildL<<<4096, 256, 0, stream>>>(Ain, An, D, Lw);

    // 3 GraphConv layers
    const int fins[3]  = {128, 64, 256};
    const int fouts[3] = {64, 256, 512};
    const float* xins[3] = {x, h0, h1};
    float* houts[3] = {h0, h1, h2};
    for (int li = 0; li < 3; ++li) {
        int fin = fins[li], fout = fouts[li];
        int base = 7 + li * 6;
        const float* gW = (const float*)d_in[base + 0];
        const float* gb = (const float*)d_in[base + 1];
        const float* gg = (const float*)d_in[base + 2];
        const float* gB = (const float*)d_in[base + 3];
        const float* gm = (const float*)d_in[base + 4];
        const float* gv = (const float*)d_in[base + 5];
        const float* xin = xins[li];
        int ld6 = 6 * fin;

        int nvec = 2 * 4096 * fin / 4;
        copy_t0<<<(nvec + 255) / 256, 256, 0, stream>>>(xin, Xc, fin);
        // T1 = L @ xin   -> Xcat col [rel*3*fin + fin]
        cheb_mm<<<dim3(fin / 64, 2, 64), 256, 0, stream>>>(
            Lw, xin, fin, 0, 0, nullptr, 0, 1.0f, Xc, ld6, 3 * fin, fin);
        // T2 = 2*L @ T1 - T0  -> Xcat col [rel*3*fin + 2*fin]
        cheb_mm<<<dim3(fin / 64, 2, 64), 256, 0, stream>>>(
            Lw, Xc, ld6, 3 * fin, fin, xin, fin, 2.0f, Xc, ld6, 3 * fin, 2 * fin);
        // fc + bias + mask + BN + relu
        fc_gemm<<<dim3(fout / 64, 64), 256, 0, stream>>>(
            Xc, gW, gb, mask, gg, gB, gm, gv, houts[li], ld6, fout);
    }

    pool_max<<<Bk, 512, 0, stream>>>(h2, pl);
    classifier<<<Bk, 256, 0, stream>>>(pl, fW1, fb1, fW2, fb2, (float*)d_out);
}

// Round 3
// 312.156 us; speedup vs baseline: 1.4407x; 1.4407x over previous
//
#include <hip/hip_runtime.h>

// ---------------- constants ----------------
#define Bk 32      // batch
#define Nn 128     // nodes
#define Cc 128     // in channels
#define HE 64      // edge hidden
#define BN_EPS 1e-5f

typedef __attribute__((ext_vector_type(8))) short short8;
typedef __attribute__((ext_vector_type(4))) float floatx4;

// workspace offsets (floats)
// edge scratch region [0 .. 2101248) is reused as T1buf in the layer loop
#define OFF_U    ((size_t)0)         // 262144
#define OFF_V    ((size_t)262144)    // 262144
#define OFF_S    ((size_t)524288)    // 524288
#define OFF_AP   ((size_t)1048576)   // 524288
#define OFF_RS   ((size_t)1572864)   // 4096
#define OFF_AN   ((size_t)1576960)   // 524288
#define OFF_T1   ((size_t)0)         // alias: 2*4096*256 = 2097152 max
#define OFF_D    ((size_t)2101248)   // 8192
#define OFF_L    ((size_t)2109440)   // 1048576
#define OFF_H0   ((size_t)3158016)   // 262144
#define OFF_H1   ((size_t)3420160)   // 1048576
#define OFF_H2   ((size_t)4468736)   // 2097152
#define OFF_XB   ((size_t)6565888)   // bf16 Xcat: 4096x1536 ushort = 3145728 floats
#define OFF_WT   ((size_t)9711616)   // bf16 Wt: 933888 ushort = 466944 floats
#define OFF_POOL ((size_t)10178560)  // 16384
// total ~10.2M floats = 40.8 MB

__device__ __forceinline__ unsigned short f2b(float f) {
    unsigned int x = __float_as_uint(f);
    unsigned int r = x + 0x7FFFu + ((x >> 16) & 1u);
    return (unsigned short)(r >> 16);
}

// ---------------- edge MLP: u = x@W1[:C] + b1, v = x@W1[C:] ----------------
__global__ __launch_bounds__(128) void edge_uv(const float* __restrict__ x,
                                               const float* __restrict__ eW1,
                                               const float* __restrict__ eb1,
                                               float* __restrict__ u, float* __restrict__ v) {
    int bn = blockIdx.x;
    int tid = threadIdx.x;
    __shared__ float xs[Cc];
    xs[tid] = x[(size_t)bn * Cc + tid];
    __syncthreads();
    int h = tid & 63;
    int which = tid >> 6;
    const float* W = eW1 + (size_t)which * Cc * HE + h;
    float acc = 0.f;
#pragma unroll 8
    for (int c = 0; c < Cc; ++c) acc += xs[c] * W[(size_t)c * HE];
    if (which == 0) u[(size_t)bn * HE + h] = acc + eb1[h];
    else            v[(size_t)bn * HE + h] = acc;
}

// ---------------- edge scores s[b,i,j] ----------------
__global__ __launch_bounds__(256) void edge_score(const float* __restrict__ u,
                                                  const float* __restrict__ v,
                                                  const float* __restrict__ eW2,
                                                  const float* __restrict__ eb2,
                                                  float* __restrict__ s) {
    __shared__ float us[16][68], vs[16][68], w2[HE];
    int b = blockIdx.z;
    int i0 = blockIdx.y * 16, j0 = blockIdx.x * 16;
    int tid = threadIdx.x;
    int r = tid >> 4, c4 = (tid & 15) * 4;
    {
        const float4 uv = *(const float4*)(u + ((size_t)(b * Nn + i0 + r)) * HE + c4);
        us[r][c4] = uv.x; us[r][c4 + 1] = uv.y; us[r][c4 + 2] = uv.z; us[r][c4 + 3] = uv.w;
        const float4 vv = *(const float4*)(v + ((size_t)(b * Nn + j0 + r)) * HE + c4);
        vs[r][c4] = vv.x; vs[r][c4 + 1] = vv.y; vs[r][c4 + 2] = vv.z; vs[r][c4 + 3] = vv.w;
    }
    if (tid < HE) w2[tid] = eW2[tid];
    __syncthreads();
    int il = tid >> 4, jl = tid & 15;
    float acc = 0.f;
#pragma unroll
    for (int h = 0; h < HE; ++h) {
        float t = us[il][h] + vs[jl][h];
        acc += fmaxf(t, 0.f) * w2[h];
    }
    s[((size_t)(b * Nn + i0 + il)) * Nn + j0 + jl] = acc + eb2[0];
}

// ---------------- A_pred (tri-masked exp) + row sums ----------------
__global__ __launch_bounds__(128) void edge_ap(const float* __restrict__ s,
                                               const float* __restrict__ mask,
                                               float* __restrict__ ap, float* __restrict__ rs) {
    int bi = blockIdx.x;
    int b = bi >> 7, i = bi & 127;
    int j = threadIdx.x;
    float mi = mask[b * Nn + i];
    float mj = mask[b * Nn + j];
    float val = 0.f;
    if (j > i && mi != 0.f && mj != 0.f) {
        float sij = s[((size_t)bi) * Nn + j];
        float sji = s[((size_t)(b * Nn + j)) * Nn + i];
        val = expf(fminf(0.5f * (sij + sji), 80.f)) * (mi * mj);
    }
    ap[((size_t)bi) * Nn + j] = val;
    __shared__ float red[128];
    red[j] = val;
    __syncthreads();
    for (int ofs = 64; ofs > 0; ofs >>= 1) {
        if (j < ofs) red[j] += red[j + ofs];
        __syncthreads();
    }
    if (j == 0) {
        float r = red[0];
        rs[bi] = (r == 0.f) ? 1.f : r;
    }
}

// ---------------- An = ap/rs + (ap/rs)^T ----------------
__global__ __launch_bounds__(128) void edge_an(const float* __restrict__ ap,
                                               const float* __restrict__ rs,
                                               float* __restrict__ An) {
    int bi = blockIdx.x;
    int b = bi >> 7, i = bi & 127;
    int j = threadIdx.x;
    float a_ij = ap[((size_t)bi) * Nn + j];
    float a_ji = ap[((size_t)(b * Nn + j)) * Nn + i];
    An[((size_t)bi) * Nn + j] = a_ij / rs[bi] + a_ji / rs[b * Nn + j];
}

// ---------------- degrees ----------------
__global__ __launch_bounds__(128) void degrees(const float* __restrict__ A,
                                               const float* __restrict__ An,
                                               float* __restrict__ D) {
    int b = blockIdx.x >> 1, rel = blockIdx.x & 1;
    int j = threadIdx.x;
    const float* Ar = (rel ? An : A) + (size_t)b * Nn * Nn;
    float sum = 0.f;
    for (int i = 0; i < Nn; ++i) sum += Ar[(size_t)i * Nn + j];
    D[(size_t)(rel * Bk + b) * Nn + j] = rsqrtf(sum + 1e-5f);
}

// ---------------- L[rel,b,i,j] = D_i * Ar_ij * D_j ----------------
__global__ __launch_bounds__(256) void buildL(const float* __restrict__ A,
                                              const float* __restrict__ An,
                                              const float* __restrict__ D,
                                              float* __restrict__ L) {
    int idx = blockIdx.x * 256 + threadIdx.x;
    int j = idx & 127, i = (idx >> 7) & 127, b = (idx >> 14) & 31, rel = idx >> 19;
    const float* Ar = rel ? An : A;
    float a = Ar[((size_t)(b * Nn + i)) * Nn + j];
    L[idx] = D[(size_t)(rel * Bk + b) * Nn + i] * a * D[(size_t)(rel * Bk + b) * Nn + j];
}

// ---------------- weights -> bf16 transposed Wt[n][k] ----------------
__global__ __launch_bounds__(256) void prep_weights(const float* __restrict__ W0,
                                                    const float* __restrict__ W1,
                                                    const float* __restrict__ W2,
                                                    unsigned short* __restrict__ Wt) {
    int e = blockIdx.x * 256 + threadIdx.x;
    if (e < 49152) {                      // 768 x 64
        int k = e >> 6, n = e & 63;
        Wt[n * 768 + k] = f2b(W0[e]);
        return;
    }
    e -= 49152;
    if (e < 98304) {                      // 384 x 256
        int k = e >> 8, n = e & 255;
        Wt[49152 + n * 384 + k] = f2b(W1[e]);
        return;
    }
    e -= 98304;
    if (e < 786432) {                     // 1536 x 512
        int k = e >> 9, n = e & 511;
        Wt[147456 + n * 1536 + k] = f2b(W2[e]);
    }
}

// ---------------- T0 copy (f32 -> bf16 Xcat slices) ----------------
__global__ __launch_bounds__(256) void copy_t0b(const float* __restrict__ xh,
                                                unsigned short* __restrict__ Xb, int fin) {
    int t = blockIdx.x * 256 + threadIdx.x;
    int e = t * 4;
    int total = 2 * 4096 * fin;
    if (e >= total) return;
    int rel = e / (4096 * fin);
    int r2 = e - rel * 4096 * fin;
    int bn = r2 / fin;
    int c = r2 - bn * fin;
    float4 val = *(const float4*)(xh + (size_t)bn * fin + c);
    ushort4 o;
    o.x = f2b(val.x); o.y = f2b(val.y); o.z = f2b(val.z); o.w = f2b(val.w);
    *(ushort4*)(Xb + (size_t)bn * 6 * fin + rel * 3 * fin + c) = o;
}

// ---------------- T1 = L @ xin : f32 to T1buf + bf16 to Xcat ----------------
__global__ __launch_bounds__(256) void cheb_t1(const float* __restrict__ L,
                                               const float* __restrict__ xin, int fin,
                                               float* __restrict__ T1,
                                               unsigned short* __restrict__ Xb) {
    int z = blockIdx.z;
    int b = z & 31, rel = z >> 5;
    const float* Lb = L + ((size_t)(rel * Bk + b)) * Nn * Nn;
    const float* Xbk = xin + (size_t)b * Nn * fin;
    int row0 = blockIdx.y * 64, col0 = blockIdx.x * 64;
    __shared__ float As[16][65];
    __shared__ float Bs[16][64];
    int tid = threadIdx.x;
    int ar = tid >> 2, ak = (tid & 3) << 2;
    int bkr = tid >> 4, bc = (tid & 15) << 2;
    int tr = (tid >> 4) << 2, tc = (tid & 15) << 2;
    float acc[4][4] = {};
    for (int k0 = 0; k0 < Nn; k0 += 16) {
        float4 av = *(const float4*)(Lb + (size_t)(row0 + ar) * Nn + k0 + ak);
        As[ak][ar] = av.x; As[ak + 1][ar] = av.y; As[ak + 2][ar] = av.z; As[ak + 3][ar] = av.w;
        float4 bv = *(const float4*)(Xbk + (size_t)(k0 + bkr) * fin + col0 + bc);
        *(float4*)&Bs[bkr][bc] = bv;
        __syncthreads();
#pragma unroll
        for (int k = 0; k < 16; ++k) {
            float a[4], bb[4];
#pragma unroll
            for (int q = 0; q < 4; ++q) { a[q] = As[k][tr + q]; bb[q] = Bs[k][tc + q]; }
#pragma unroll
            for (int ii = 0; ii < 4; ++ii)
#pragma unroll
                for (int jj = 0; jj < 4; ++jj) acc[ii][jj] = fmaf(a[ii], bb[jj], acc[ii][jj]);
        }
        __syncthreads();
    }
    int ld6 = 6 * fin;
#pragma unroll
    for (int ii = 0; ii < 4; ++ii) {
        int row = row0 + tr + ii;
#pragma unroll
        for (int jj = 0; jj < 4; ++jj) {
            int col = col0 + tc + jj;
            float vout = acc[ii][jj];
            T1[((size_t)rel * 4096 + b * Nn + row) * fin + col] = vout;
            Xb[(size_t)(b * Nn + row) * ld6 + rel * 3 * fin + fin + col] = f2b(vout);
        }
    }
}

// ---------------- T2 = 2*L @ T1 - T0 : bf16 to Xcat ----------------
__global__ __launch_bounds__(256) void cheb_t2(const float* __restrict__ L,
                                               const float* __restrict__ T1,
                                               const float* __restrict__ xin, int fin,
                                               unsigned short* __restrict__ Xb) {
    int z = blockIdx.z;
    int b = z & 31, rel = z >> 5;
    const float* Lb = L + ((size_t)(rel * Bk + b)) * Nn * Nn;
    const float* Xbk = T1 + ((size_t)rel * 4096 + b * Nn) * fin;
    int row0 = blockIdx.y * 64, col0 = blockIdx.x * 64;
    __shared__ float As[16][65];
    __shared__ float Bs[16][64];
    int tid = threadIdx.x;
    int ar = tid >> 2, ak = (tid & 3) << 2;
    int bkr = tid >> 4, bc = (tid & 15) << 2;
    int tr = (tid >> 4) << 2, tc = (tid & 15) << 2;
    float acc[4][4] = {};
    for (int k0 = 0; k0 < Nn; k0 += 16) {
        float4 av = *(const float4*)(Lb + (size_t)(row0 + ar) * Nn + k0 + ak);
        As[ak][ar] = av.x; As[ak + 1][ar] = av.y; As[ak + 2][ar] = av.z; As[ak + 3][ar] = av.w;
        float4 bv = *(const float4*)(Xbk + (size_t)(k0 + bkr) * fin + col0 + bc);
        *(float4*)&Bs[bkr][bc] = bv;
        __syncthreads();
#pragma unroll
        for (int k = 0; k < 16; ++k) {
            float a[4], bb[4];
#pragma unroll
            for (int q = 0; q < 4; ++q) { a[q] = As[k][tr + q]; bb[q] = Bs[k][tc + q]; }
#pragma unroll
            for (int ii = 0; ii < 4; ++ii)
#pragma unroll
                for (int jj = 0; jj < 4; ++jj) acc[ii][jj] = fmaf(a[ii], bb[jj], acc[ii][jj]);
        }
        __syncthreads();
    }
    int ld6 = 6 * fin;
#pragma unroll
    for (int ii = 0; ii < 4; ++ii) {
        int row = row0 + tr + ii;
#pragma unroll
        for (int jj = 0; jj < 4; ++jj) {
            int col = col0 + tc + jj;
            float vout = 2.0f * acc[ii][jj] - xin[(size_t)(b * Nn + row) * fin + col];
            Xb[(size_t)(b * Nn + row) * ld6 + rel * 3 * fin + 2 * fin + col] = f2b(vout);
        }
    }
}

// ---------------- fc via bf16 MFMA + fused bias/mask/BN/relu ----------------
// block: 256 threads = 4 waves; wave computes RT row-tiles(16) x 4 col-tiles(16)
// block tile: (RT*64) rows x 64 cols.  K-chunk 32.
template <int RT>
__global__ __launch_bounds__(256) void fc_mfma(const unsigned short* __restrict__ Xb,
                                               const unsigned short* __restrict__ Wt,
                                               const float* __restrict__ bias,
                                               const float* __restrict__ mask,
                                               const float* __restrict__ bnG,
                                               const float* __restrict__ bnB,
                                               const float* __restrict__ bnM,
                                               const float* __restrict__ bnV,
                                               float* __restrict__ out, int Kd, int F) {
    __shared__ __align__(16) unsigned short As[RT * 64 * 40];  // rows padded to 40
    __shared__ __align__(16) unsigned short Bs[64 * 40];
    int tid = threadIdx.x;
    int w = tid >> 6, lane = tid & 63, quad = lane >> 4, lr = lane & 15;
    int row0 = blockIdx.y * (RT * 64), col0 = blockIdx.x * 64;

    floatx4 acc[RT][4];
#pragma unroll
    for (int rt = 0; rt < RT; ++rt)
#pragma unroll
        for (int ct = 0; ct < 4; ++ct) acc[rt][ct] = (floatx4){0.f, 0.f, 0.f, 0.f};

    int arow[RT], asub[RT];
#pragma unroll
    for (int i = 0; i < RT; ++i) { int ch = tid + i * 256; arow[i] = ch >> 2; asub[i] = ch & 3; }
    int brow = tid >> 2, bsub = tid & 3;

    for (int k0 = 0; k0 < Kd; k0 += 32) {
        short8 ra[RT];
#pragma unroll
        for (int i = 0; i < RT; ++i)
            ra[i] = *(const short8*)(Xb + (size_t)(row0 + arow[i]) * Kd + k0 + asub[i] * 8);
        short8 rb = *(const short8*)(Wt + (size_t)(col0 + brow) * Kd + k0 + bsub * 8);
        __syncthreads();   // previous iteration's frag reads complete
#pragma unroll
        for (int i = 0; i < RT; ++i)
            *(short8*)&As[arow[i] * 40 + asub[i] * 8] = ra[i];
        *(short8*)&Bs[brow * 40 + bsub * 8] = rb;
        __syncthreads();
        short8 a[RT], b[4];
#pragma unroll
        for (int rt = 0; rt < RT; ++rt)
            a[rt] = *(const short8*)&As[(w * RT * 16 + rt * 16 + lr) * 40 + quad * 8];
#pragma unroll
        for (int ct = 0; ct < 4; ++ct)
            b[ct] = *(const short8*)&Bs[(ct * 16 + lr) * 40 + quad * 8];
#pragma unroll
        for (int rt = 0; rt < RT; ++rt)
#pragma unroll
            for (int ct = 0; ct < 4; ++ct)
                acc[rt][ct] = __builtin_amdgcn_mfma_f32_16x16x32_bf16(a[rt], b[ct], acc[rt][ct], 0, 0, 0);
    }

#pragma unroll
    for (int rt = 0; rt < RT; ++rt) {
        int rbase = row0 + w * RT * 16 + rt * 16 + quad * 4;
#pragma unroll
        for (int ct = 0; ct < 4; ++ct) {
            int col = col0 + ct * 16 + lr;
            float bi = bias[col];
            float sc = rsqrtf(bnV[col] + BN_EPS) * bnG[col];
            float bm = bnM[col], bb = bnB[col];
#pragma unroll
            for (int reg = 0; reg < 4; ++reg) {
                int row = rbase + reg;
                float h = acc[rt][ct][reg] + bi;
                h *= mask[row];
                h = (h - bm) * sc + bb;
                out[(size_t)row * F + col] = fmaxf(h, 0.f);
            }
        }
    }
}

// ---------------- max pool over nodes ----------------
__global__ __launch_bounds__(512) void pool_max(const float* __restrict__ h2, float* __restrict__ pooled) {
    int b = blockIdx.x;
    int f = threadIdx.x;
    const float* p = h2 + (size_t)b * Nn * 512 + f;
    float m = p[0];
    for (int n = 1; n < Nn; ++n) m = fmaxf(m, p[(size_t)n * 512]);
    pooled[(size_t)b * 512 + f] = m;
}

// ---------------- classifier ----------------
__global__ __launch_bounds__(256) void classifier(const float* __restrict__ pooled,
                                                  const float* __restrict__ fW1,
                                                  const float* __restrict__ fb1,
                                                  const float* __restrict__ fW2,
                                                  const float* __restrict__ fb2,
                                                  float* __restrict__ out) {
    int b = blockIdx.x;
    int tid = threadIdx.x;
    __shared__ float ps[512], hs[256];
    ps[tid] = pooled[(size_t)b * 512 + tid];
    ps[tid + 256] = pooled[(size_t)b * 512 + 256 + tid];
    __syncthreads();
    float acc = fb1[tid];
    for (int c = 0; c < 512; ++c) acc += ps[c] * fW1[(size_t)c * 256 + tid];
    hs[tid] = acc;
    __syncthreads();
    if (tid < 10) {
        float o = fb2[tid];
        for (int h = 0; h < 256; ++h) o += hs[h] * fW2[(size_t)h * 10 + tid];
        out[(size_t)b * 10 + tid] = o;
    }
}

extern "C" void kernel_launch(void* const* d_in, const int* in_sizes, int n_in,
                              void* d_out, int out_size, void* d_ws, size_t ws_size,
                              hipStream_t stream) {
    const float* x    = (const float*)d_in[0];
    const float* Ain  = (const float*)d_in[1];
    const float* mask = (const float*)d_in[2];
    const float* eW1  = (const float*)d_in[3];
    const float* eb1  = (const float*)d_in[4];
    const float* eW2  = (const float*)d_in[5];
    const float* eb2  = (const float*)d_in[6];
    const float* fW1  = (const float*)d_in[25];
    const float* fb1  = (const float*)d_in[26];
    const float* fW2  = (const float*)d_in[27];
    const float* fb2  = (const float*)d_in[28];

    float* ws = (float*)d_ws;
    float* u  = ws + OFF_U;
    float* v  = ws + OFF_V;
    float* s  = ws + OFF_S;
    float* ap = ws + OFF_AP;
    float* rs = ws + OFF_RS;
    float* An = ws + OFF_AN;
    float* T1 = ws + OFF_T1;
    float* D  = ws + OFF_D;
    float* Lw = ws + OFF_L;
    float* h0 = ws + OFF_H0;
    float* h1 = ws + OFF_H1;
    float* h2 = ws + OFF_H2;
    unsigned short* Xb = (unsigned short*)(ws + OFF_XB);
    unsigned short* Wt = (unsigned short*)(ws + OFF_WT);
    float* pl = ws + OFF_POOL;

    // weights prep (bf16 + transpose) — independent, launch first
    prep_weights<<<3648, 256, 0, stream>>>((const float*)d_in[7], (const float*)d_in[13],
                                           (const float*)d_in[19], Wt);

    // edge adjacency
    edge_uv<<<Bk * Nn, 128, 0, stream>>>(x, eW1, eb1, u, v);
    edge_score<<<dim3(8, 8, Bk), 256, 0, stream>>>(u, v, eW2, eb2, s);
    edge_ap<<<Bk * Nn, 128, 0, stream>>>(s, mask, ap, rs);
    edge_an<<<Bk * Nn, 128, 0, stream>>>(ap, rs, An);

    // Laplacians
    degrees<<<Bk * 2, 128, 0, stream>>>(Ain, An, D);
    buildL<<<4096, 256, 0, stream>>>(Ain, An, D, Lw);

    // 3 GraphConv layers
    const int fins[3]  = {128, 64, 256};
    const int fouts[3] = {64, 256, 512};
    const float* xins[3] = {x, h0, h1};
    float* houts[3] = {h0, h1, h2};
    const unsigned short* Wts[3] = {Wt, Wt + 49152, Wt + 147456};
    for (int li = 0; li < 3; ++li) {
        int fin = fins[li], fout = fouts[li];
        int base = 7 + li * 6;
        const float* gb = (const float*)d_in[base + 1];
        const float* gg = (const float*)d_in[base + 2];
        const float* gB = (const float*)d_in[base + 3];
        const float* gm = (const float*)d_in[base + 4];
        const float* gv = (const float*)d_in[base + 5];
        const float* xin = xins[li];

        int nvec = 2 * 4096 * fin / 4;
        copy_t0b<<<(nvec + 255) / 256, 256, 0, stream>>>(xin, Xb, fin);
        cheb_t1<<<dim3(fin / 64, 2, 64), 256, 0, stream>>>(Lw, xin, fin, T1, Xb);
        cheb_t2<<<dim3(fin / 64, 2, 64), 256, 0, stream>>>(Lw, T1, xin, fin, Xb);
        int Kd = 6 * fin;
        if (li == 0)
            fc_mfma<1><<<dim3(fout / 64, 4096 / 64), 256, 0, stream>>>(
                Xb, Wts[li], gb, mask, gg, gB, gm, gv, houts[li], Kd, fout);
        else
            fc_mfma<2><<<dim3(fout / 64, 4096 / 128), 256, 0, stream>>>(
                Xb, Wts[li], gb, mask, gg, gB, gm, gv, houts[li], Kd, fout);
    }

    pool_max<<<Bk, 512, 0, stream>>>(h2, pl);
    classifier<<<Bk, 256, 0, stream>>>(pl, fW1, fb1, fW2, fb2, (float*)d_out);
}

// Round 4
// 286.386 us; speedup vs baseline: 1.5704x; 1.0900x over previous
//
#include <hip/hip_runtime.h>

// ---------------- constants ----------------
#define Bk 32      // batch
#define Nn 128     // nodes
#define Cc 128     // in channels
#define HE 64      // edge hidden
#define BN_EPS 1e-5f

typedef __attribute__((ext_vector_type(8))) short short8;
typedef __attribute__((ext_vector_type(4))) float floatx4;

// workspace offsets (floats)
#define OFF_U    ((size_t)0)         // 262144
#define OFF_V    ((size_t)262144)    // 262144
#define OFF_S    ((size_t)524288)    // 524288
#define OFF_AN   ((size_t)1048576)   // 524288
#define OFF_LB   ((size_t)1572864)   // 524288 floats = 1048576 ushort (bf16 L, 2 rel x 32 b x 128 x 128)
#define OFF_H0   ((size_t)2097152)   // 262144
#define OFF_H1   ((size_t)2359296)   // 1048576
#define OFF_H2   ((size_t)3407872)   // 2097152
#define OFF_XB   ((size_t)5505024)   // 3145728 floats = 6291456 ushort (bf16 Xcat 4096x1536)
#define OFF_WT   ((size_t)8650752)   // 466944 floats = 933888 ushort (bf16 Wt)
// total 9117696 floats = 36.5 MB

__device__ __forceinline__ unsigned short f2b(float f) {
    unsigned int x = __float_as_uint(f);
    unsigned int r = x + 0x7FFFu + ((x >> 16) & 1u);
    return (unsigned short)(r >> 16);
}

// ---------------- edge MLP: u = x@W1[:C] + b1, v = x@W1[C:] ----------------
__global__ __launch_bounds__(128) void edge_uv(const float* __restrict__ x,
                                               const float* __restrict__ eW1,
                                               const float* __restrict__ eb1,
                                               float* __restrict__ u, float* __restrict__ v) {
    int bn = blockIdx.x;
    int tid = threadIdx.x;
    __shared__ float xs[Cc];
    xs[tid] = x[(size_t)bn * Cc + tid];
    __syncthreads();
    int h = tid & 63;
    int which = tid >> 6;
    const float* W = eW1 + (size_t)which * Cc * HE + h;
    float acc = 0.f;
#pragma unroll 8
    for (int c = 0; c < Cc; ++c) acc += xs[c] * W[(size_t)c * HE];
    if (which == 0) u[(size_t)bn * HE + h] = acc + eb1[h];
    else            v[(size_t)bn * HE + h] = acc;
}

// ---------------- edge scores s[b,i,j] ----------------
__global__ __launch_bounds__(256) void edge_score(const float* __restrict__ u,
                                                  const float* __restrict__ v,
                                                  const float* __restrict__ eW2,
                                                  const float* __restrict__ eb2,
                                                  float* __restrict__ s) {
    __shared__ float us[16][68], vs[16][68], w2[HE];
    int b = blockIdx.z;
    int i0 = blockIdx.y * 16, j0 = blockIdx.x * 16;
    int tid = threadIdx.x;
    int r = tid >> 4, c4 = (tid & 15) * 4;
    {
        const float4 uv = *(const float4*)(u + ((size_t)(b * Nn + i0 + r)) * HE + c4);
        us[r][c4] = uv.x; us[r][c4 + 1] = uv.y; us[r][c4 + 2] = uv.z; us[r][c4 + 3] = uv.w;
        const float4 vv = *(const float4*)(v + ((size_t)(b * Nn + j0 + r)) * HE + c4);
        vs[r][c4] = vv.x; vs[r][c4 + 1] = vv.y; vs[r][c4 + 2] = vv.z; vs[r][c4 + 3] = vv.w;
    }
    if (tid < HE) w2[tid] = eW2[tid];
    __syncthreads();
    int il = tid >> 4, jl = tid & 15;
    float acc = 0.f;
#pragma unroll
    for (int h = 0; h < HE; ++h) {
        float t = us[il][h] + vs[jl][h];
        acc += fmaxf(t, 0.f) * w2[h];
    }
    s[((size_t)(b * Nn + i0 + il)) * Nn + j0 + jl] = acc + eb2[0];
}

// ---------------- fused: A_pred + row sums + An (one block per batch) ----------------
__global__ __launch_bounds__(256) void edge_apan(const float* __restrict__ s,
                                                 const float* __restrict__ mask,
                                                 float* __restrict__ An) {
    __shared__ float apS[128][129];
    __shared__ float rsS[128];
    __shared__ float msk[128];
    int b = blockIdx.x, tid = threadIdx.x;
    const float* sb = s + (size_t)b * Nn * Nn;
    if (tid < 128) msk[tid] = mask[b * Nn + tid];
    __syncthreads();
#pragma unroll
    for (int k = 0; k < 64; ++k) {
        int idx = tid + k * 256;
        int i = idx >> 7, j = idx & 127;
        float val = 0.f;
        if (j > i && msk[i] != 0.f && msk[j] != 0.f) {
            val = expf(fminf(0.5f * (sb[idx] + sb[j * Nn + i]), 80.f));
        }
        apS[i][j] = val;
    }
    __syncthreads();
    if (tid < 128) {
        float r = 0.f;
        for (int j = 0; j < 128; ++j) r += apS[tid][j];
        rsS[tid] = (r == 0.f) ? 1.f : r;
    }
    __syncthreads();
    float* Ab = An + (size_t)b * Nn * Nn;
#pragma unroll
    for (int k = 0; k < 64; ++k) {
        int idx = tid + k * 256;
        int i = idx >> 7, j = idx & 127;
        Ab[idx] = apS[i][j] / rsS[i] + apS[j][i] / rsS[j];
    }
}

// ---------------- fused degrees + L build (bf16 out), one block per (b,rel) ----------------
__global__ __launch_bounds__(256) void buildLb(const float* __restrict__ A,
                                               const float* __restrict__ An,
                                               unsigned short* __restrict__ Lb) {
    int b = blockIdx.x & 31, rel = blockIdx.x >> 5;
    const float* Ar = (rel ? An : A) + (size_t)b * Nn * Nn;
    __shared__ float part[256];
    __shared__ float Ds[128];
    int tid = threadIdx.x;
    int j = tid & 127, half = tid >> 7;
    float sum = 0.f;
    for (int i = half * 64; i < half * 64 + 64; ++i) sum += Ar[i * Nn + j];
    part[tid] = sum;
    __syncthreads();
    if (tid < 128) Ds[tid] = rsqrtf(part[tid] + part[tid + 128] + 1e-5f);
    __syncthreads();
    unsigned short* Lo = Lb + ((size_t)(rel * Bk + b)) * Nn * Nn;
#pragma unroll
    for (int k = 0; k < 64; ++k) {
        int idx = tid + k * 256;
        int i = idx >> 7, jj = idx & 127;
        Lo[idx] = f2b(Ds[i] * Ar[idx] * Ds[jj]);
    }
}

// ---------------- weights -> bf16 transposed Wt[n][k] ----------------
__global__ __launch_bounds__(256) void prep_weights(const float* __restrict__ W0,
                                                    const float* __restrict__ W1,
                                                    const float* __restrict__ W2,
                                                    unsigned short* __restrict__ Wt) {
    int e = blockIdx.x * 256 + threadIdx.x;
    if (e < 49152) {                      // 768 x 64
        int k = e >> 6, n = e & 63;
        Wt[n * 768 + k] = f2b(W0[e]);
        return;
    }
    e -= 49152;
    if (e < 98304) {                      // 384 x 256
        int k = e >> 8, n = e & 255;
        Wt[49152 + n * 384 + k] = f2b(W1[e]);
        return;
    }
    e -= 98304;
    if (e < 786432) {                     // 1536 x 512
        int k = e >> 9, n = e & 511;
        Wt[147456 + n * 1536 + k] = f2b(W2[e]);
    }
}

// ---------------- fused Chebyshev staging (per layer) ----------------
// Block: one (b, rel, 64-col tile). Computes T0 copy, T1 = L@X, T2 = 2*L@T1 - T0,
// all via bf16 MFMA, writing bf16 slices of Xcat.
template <int FIN>
__global__ __launch_bounds__(256) void cheb_fused(const unsigned short* __restrict__ Lb,
                                                  const float* __restrict__ xin,
                                                  unsigned short* __restrict__ Xb) {
    constexpr int LDK = 136;     // ushort stride: 2-way-max bank aliasing on frag reads
    __shared__ __align__(16) unsigned short Ls[128 * LDK];
    __shared__ __align__(16) unsigned short XsT[64 * LDK];   // [col][node]
    __shared__ __align__(16) unsigned short T1T[64 * LDK];   // [col][node]
    int z = blockIdx.y;
    int b = z & 31, rel = z >> 5;
    int c0 = blockIdx.x * 64;
    int tid = threadIdx.x;
    int w = tid >> 6, lane = tid & 63, quad = lane >> 4, lr = lane & 15;
    const unsigned short* Lp = Lb + ((size_t)(rel * Bk + b)) * Nn * Nn;
    const float* Xp = xin + (size_t)b * Nn * FIN;
    const int ld6 = 6 * FIN;
    unsigned short* Xo = Xb + (size_t)b * Nn * ld6 + rel * 3 * FIN;

    // ---- load L -> Ls ----
#pragma unroll
    for (int i = 0; i < 16; ++i) {
        int idx = tid + i * 256;                 // ushort4 index over 4096
        int row = idx >> 5, col4 = (idx & 31) << 2;
        ushort4 val = *(const ushort4*)(Lp + row * Nn + col4);
        *(ushort4*)&Ls[row * LDK + col4] = val;
    }
    // ---- load X col-slice -> XsT (transposed bf16), write T0 slice ----
    {
        int node = tid >> 1, cb = (tid & 1) * 32;
        const float* xr = Xp + (size_t)node * FIN + c0 + cb;
        unsigned short* t0w = Xo + (size_t)node * ld6 + c0 + cb;
#pragma unroll
        for (int i = 0; i < 8; ++i) {
            float4 vv = *(const float4*)(xr + i * 4);
            ushort4 o;
            o.x = f2b(vv.x); o.y = f2b(vv.y); o.z = f2b(vv.z); o.w = f2b(vv.w);
            *(ushort4*)(t0w + i * 4) = o;
            XsT[(cb + i * 4 + 0) * LDK + node] = o.x;
            XsT[(cb + i * 4 + 1) * LDK + node] = o.y;
            XsT[(cb + i * 4 + 2) * LDK + node] = o.z;
            XsT[(cb + i * 4 + 3) * LDK + node] = o.w;
        }
    }
    __syncthreads();

    // ---- T1 = L @ Xslice : wave w -> row-tiles {2w, 2w+1} x 4 col-tiles ----
    floatx4 acc[2][4];
#pragma unroll
    for (int rt = 0; rt < 2; ++rt)
#pragma unroll
        for (int ct = 0; ct < 4; ++ct) acc[rt][ct] = (floatx4){0.f, 0.f, 0.f, 0.f};
#pragma unroll
    for (int kc = 0; kc < 4; ++kc) {
        short8 a[2], bb[4];
#pragma unroll
        for (int rt = 0; rt < 2; ++rt)
            a[rt] = *(const short8*)&Ls[((w * 2 + rt) * 16 + lr) * LDK + kc * 32 + quad * 8];
#pragma unroll
        for (int ct = 0; ct < 4; ++ct)
            bb[ct] = *(const short8*)&XsT[(ct * 16 + lr) * LDK + kc * 32 + quad * 8];
#pragma unroll
        for (int rt = 0; rt < 2; ++rt)
#pragma unroll
            for (int ct = 0; ct < 4; ++ct)
                acc[rt][ct] = __builtin_amdgcn_mfma_f32_16x16x32_bf16(a[rt], bb[ct], acc[rt][ct], 0, 0, 0);
    }
    // write T1^T to LDS (bf16)
#pragma unroll
    for (int rt = 0; rt < 2; ++rt) {
        int rb = (w * 2 + rt) * 16 + quad * 4;
#pragma unroll
        for (int ct = 0; ct < 4; ++ct) {
            int col = ct * 16 + lr;
            ushort4 o;
            o.x = f2b(acc[rt][ct][0]); o.y = f2b(acc[rt][ct][1]);
            o.z = f2b(acc[rt][ct][2]); o.w = f2b(acc[rt][ct][3]);
            *(ushort4*)&T1T[col * LDK + rb] = o;
        }
    }
    __syncthreads();

    // ---- T1 global copy (coalesced) ----
    {
        int node = tid >> 1, cb = (tid & 1) * 32;
        unsigned short* t1w = Xo + (size_t)node * ld6 + FIN + c0 + cb;
#pragma unroll
        for (int i = 0; i < 8; ++i) {
            ushort4 o;
            o.x = T1T[(cb + i * 4 + 0) * LDK + node];
            o.y = T1T[(cb + i * 4 + 1) * LDK + node];
            o.z = T1T[(cb + i * 4 + 2) * LDK + node];
            o.w = T1T[(cb + i * 4 + 3) * LDK + node];
            *(ushort4*)(t1w + i * 4) = o;
        }
    }
    // ---- T2 = 2 * L @ T1 - T0 ----
    floatx4 acc2[2][4];
#pragma unroll
    for (int rt = 0; rt < 2; ++rt)
#pragma unroll
        for (int ct = 0; ct < 4; ++ct) acc2[rt][ct] = (floatx4){0.f, 0.f, 0.f, 0.f};
#pragma unroll
    for (int kc = 0; kc < 4; ++kc) {
        short8 a[2], bb[4];
#pragma unroll
        for (int rt = 0; rt < 2; ++rt)
            a[rt] = *(const short8*)&Ls[((w * 2 + rt) * 16 + lr) * LDK + kc * 32 + quad * 8];
#pragma unroll
        for (int ct = 0; ct < 4; ++ct)
            bb[ct] = *(const short8*)&T1T[(ct * 16 + lr) * LDK + kc * 32 + quad * 8];
#pragma unroll
        for (int rt = 0; rt < 2; ++rt)
#pragma unroll
            for (int ct = 0; ct < 4; ++ct)
                acc2[rt][ct] = __builtin_amdgcn_mfma_f32_16x16x32_bf16(a[rt], bb[ct], acc2[rt][ct], 0, 0, 0);
    }
    // epilogue: subtract exact f32 T0 from global, stash T2^T into XsT (reused)
#pragma unroll
    for (int rt = 0; rt < 2; ++rt) {
        int rb = (w * 2 + rt) * 16 + quad * 4;
#pragma unroll
        for (int ct = 0; ct < 4; ++ct) {
            int col = ct * 16 + lr;
            ushort4 o;
            float t0a = Xp[(size_t)(rb + 0) * FIN + c0 + col];
            float t0b = Xp[(size_t)(rb + 1) * FIN + c0 + col];
            float t0c = Xp[(size_t)(rb + 2) * FIN + c0 + col];
            float t0d = Xp[(size_t)(rb + 3) * FIN + c0 + col];
            o.x = f2b(2.f * acc2[rt][ct][0] - t0a);
            o.y = f2b(2.f * acc2[rt][ct][1] - t0b);
            o.z = f2b(2.f * acc2[rt][ct][2] - t0c);
            o.w = f2b(2.f * acc2[rt][ct][3] - t0d);
            *(ushort4*)&XsT[col * LDK + rb] = o;
        }
    }
    __syncthreads();
    // ---- T2 global copy (coalesced) ----
    {
        int node = tid >> 1, cb = (tid & 1) * 32;
        unsigned short* t2w = Xo + (size_t)node * ld6 + 2 * FIN + c0 + cb;
#pragma unroll
        for (int i = 0; i < 8; ++i) {
            ushort4 o;
            o.x = XsT[(cb + i * 4 + 0) * LDK + node];
            o.y = XsT[(cb + i * 4 + 1) * LDK + node];
            o.z = XsT[(cb + i * 4 + 2) * LDK + node];
            o.w = XsT[(cb + i * 4 + 3) * LDK + node];
            *(ushort4*)(t2w + i * 4) = o;
        }
    }
}

// ---------------- fc via bf16 MFMA + fused bias/mask/BN/relu ----------------
template <int RT>
__global__ __launch_bounds__(256) void fc_mfma(const unsigned short* __restrict__ Xb,
                                               const unsigned short* __restrict__ Wt,
                                               const float* __restrict__ bias,
                                               const float* __restrict__ mask,
                                               const float* __restrict__ bnG,
                                               const float* __restrict__ bnB,
                                               const float* __restrict__ bnM,
                                               const float* __restrict__ bnV,
                                               float* __restrict__ out, int Kd, int F) {
    __shared__ __align__(16) unsigned short As[RT * 64 * 40];
    __shared__ __align__(16) unsigned short Bs[64 * 40];
    int tid = threadIdx.x;
    int w = tid >> 6, lane = tid & 63, quad = lane >> 4, lr = lane & 15;
    int row0 = blockIdx.y * (RT * 64), col0 = blockIdx.x * 64;

    floatx4 acc[RT][4];
#pragma unroll
    for (int rt = 0; rt < RT; ++rt)
#pragma unroll
        for (int ct = 0; ct < 4; ++ct) acc[rt][ct] = (floatx4){0.f, 0.f, 0.f, 0.f};

    int arow[RT], asub[RT];
#pragma unroll
    for (int i = 0; i < RT; ++i) { int ch = tid + i * 256; arow[i] = ch >> 2; asub[i] = ch & 3; }
    int brow = tid >> 2, bsub = tid & 3;

    for (int k0 = 0; k0 < Kd; k0 += 32) {
        short8 ra[RT];
#pragma unroll
        for (int i = 0; i < RT; ++i)
            ra[i] = *(const short8*)(Xb + (size_t)(row0 + arow[i]) * Kd + k0 + asub[i] * 8);
        short8 rb = *(const short8*)(Wt + (size_t)(col0 + brow) * Kd + k0 + bsub * 8);
        __syncthreads();
#pragma unroll
        for (int i = 0; i < RT; ++i)
            *(short8*)&As[arow[i] * 40 + asub[i] * 8] = ra[i];
        *(short8*)&Bs[brow * 40 + bsub * 8] = rb;
        __syncthreads();
        short8 a[RT], b[4];
#pragma unroll
        for (int rt = 0; rt < RT; ++rt)
            a[rt] = *(const short8*)&As[(w * RT * 16 + rt * 16 + lr) * 40 + quad * 8];
#pragma unroll
        for (int ct = 0; ct < 4; ++ct)
            b[ct] = *(const short8*)&Bs[(ct * 16 + lr) * 40 + quad * 8];
#pragma unroll
        for (int rt = 0; rt < RT; ++rt)
#pragma unroll
            for (int ct = 0; ct < 4; ++ct)
                acc[rt][ct] = __builtin_amdgcn_mfma_f32_16x16x32_bf16(a[rt], b[ct], acc[rt][ct], 0, 0, 0);
    }

#pragma unroll
    for (int rt = 0; rt < RT; ++rt) {
        int rbase = row0 + w * RT * 16 + rt * 16 + quad * 4;
#pragma unroll
        for (int ct = 0; ct < 4; ++ct) {
            int col = col0 + ct * 16 + lr;
            float bi = bias[col];
            float sc = rsqrtf(bnV[col] + BN_EPS) * bnG[col];
            float bm = bnM[col], bb = bnB[col];
#pragma unroll
            for (int reg = 0; reg < 4; ++reg) {
                int row = rbase + reg;
                float h = acc[rt][ct][reg] + bi;
                h *= mask[row];
                h = (h - bm) * sc + bb;
                out[(size_t)row * F + col] = fmaxf(h, 0.f);
            }
        }
    }
}

// ---------------- fused max-pool + classifier (one block per batch) ----------------
__global__ __launch_bounds__(256) void pool_cls(const float* __restrict__ h2,
                                                const float* __restrict__ fW1,
                                                const float* __restrict__ fb1,
                                                const float* __restrict__ fW2,
                                                const float* __restrict__ fb2,
                                                float* __restrict__ out) {
    int b = blockIdx.x;
    int tid = threadIdx.x;
    __shared__ float ps[512], hs[256];
    const float* p = h2 + (size_t)b * Nn * 512;
    float m1 = p[tid], m2 = p[tid + 256];
    for (int n = 1; n < Nn; ++n) {
        m1 = fmaxf(m1, p[(size_t)n * 512 + tid]);
        m2 = fmaxf(m2, p[(size_t)n * 512 + tid + 256]);
    }
    ps[tid] = m1;
    ps[tid + 256] = m2;
    __syncthreads();
    float acc = fb1[tid];
    for (int c = 0; c < 512; ++c) acc += ps[c] * fW1[(size_t)c * 256 + tid];
    hs[tid] = acc;
    __syncthreads();
    if (tid < 10) {
        float o = fb2[tid];
        for (int h = 0; h < 256; ++h) o += hs[h] * fW2[(size_t)h * 10 + tid];
        out[(size_t)b * 10 + tid] = o;
    }
}

extern "C" void kernel_launch(void* const* d_in, const int* in_sizes, int n_in,
                              void* d_out, int out_size, void* d_ws, size_t ws_size,
                              hipStream_t stream) {
    const float* x    = (const float*)d_in[0];
    const float* Ain  = (const float*)d_in[1];
    const float* mask = (const float*)d_in[2];
    const float* eW1  = (const float*)d_in[3];
    const float* eb1  = (const float*)d_in[4];
    const float* eW2  = (const float*)d_in[5];
    const float* eb2  = (const float*)d_in[6];
    const float* fW1  = (const float*)d_in[25];
    const float* fb1  = (const float*)d_in[26];
    const float* fW2  = (const float*)d_in[27];
    const float* fb2  = (const float*)d_in[28];

    float* ws = (float*)d_ws;
    float* u  = ws + OFF_U;
    float* v  = ws + OFF_V;
    float* s  = ws + OFF_S;
    float* An = ws + OFF_AN;
    unsigned short* Lb = (unsigned short*)(ws + OFF_LB);
    float* h0 = ws + OFF_H0;
    float* h1 = ws + OFF_H1;
    float* h2 = ws + OFF_H2;
    unsigned short* Xb = (unsigned short*)(ws + OFF_XB);
    unsigned short* Wt = (unsigned short*)(ws + OFF_WT);

    // weights prep (independent)
    prep_weights<<<3648, 256, 0, stream>>>((const float*)d_in[7], (const float*)d_in[13],
                                           (const float*)d_in[19], Wt);

    // edge adjacency
    edge_uv<<<Bk * Nn, 128, 0, stream>>>(x, eW1, eb1, u, v);
    edge_score<<<dim3(8, 8, Bk), 256, 0, stream>>>(u, v, eW2, eb2, s);
    edge_apan<<<Bk, 256, 0, stream>>>(s, mask, An);

    // Laplacians (bf16), fused degree computation
    buildLb<<<Bk * 2, 256, 0, stream>>>(Ain, An, Lb);

    // 3 GraphConv layers
    const float* xins[3] = {x, h0, h1};
    float* houts[3] = {h0, h1, h2};
    const unsigned short* Wts[3] = {Wt, Wt + 49152, Wt + 147456};
    const int Kds[3] = {768, 384, 1536};
    const int fouts[3] = {64, 256, 512};
    for (int li = 0; li < 3; ++li) {
        int base = 7 + li * 6;
        const float* gb = (const float*)d_in[base + 1];
        const float* gg = (const float*)d_in[base + 2];
        const float* gB = (const float*)d_in[base + 3];
        const float* gm = (const float*)d_in[base + 4];
        const float* gv = (const float*)d_in[base + 5];

        if (li == 0)      cheb_fused<128><<<dim3(2, 64), 256, 0, stream>>>(Lb, xins[li], Xb);
        else if (li == 1) cheb_fused<64><<<dim3(1, 64), 256, 0, stream>>>(Lb, xins[li], Xb);
        else              cheb_fused<256><<<dim3(4, 64), 256, 0, stream>>>(Lb, xins[li], Xb);

        if (li == 0)
            fc_mfma<1><<<dim3(fouts[li] / 64, 64), 256, 0, stream>>>(
                Xb, Wts[li], gb, mask, gg, gB, gm, gv, houts[li], Kds[li], fouts[li]);
        else
            fc_mfma<2><<<dim3(fouts[li] / 64, 32), 256, 0, stream>>>(
                Xb, Wts[li], gb, mask, gg, gB, gm, gv, houts[li], Kds[li], fouts[li]);
    }

    pool_cls<<<Bk, 256, 0, stream>>>(h2, fW1, fb1, fW2, fb2, (float*)d_out);
}

// Round 5
// 269.158 us; speedup vs baseline: 1.6709x; 1.0640x over previous
//
#include <hip/hip_runtime.h>

// ---------------- constants ----------------
#define Bk 32      // batch
#define Nn 128     // nodes
#define Cc 128     // in channels
#define HE 64      // edge hidden
#define BN_EPS 1e-5f

typedef __attribute__((ext_vector_type(8))) short short8;
typedef __attribute__((ext_vector_type(4))) float floatx4;

// workspace offsets (floats)
#define OFF_UV   ((size_t)0)         // 524288  uv f32 [4096][128] (u cols 0-63, v cols 64-127)
#define OFF_S    ((size_t)524288)    // 524288  scores
#define OFF_LB   ((size_t)1048576)   // 524288 f = 1048576 ushort bf16 L [2 rel][32 b][128][128]
#define OFF_H0   ((size_t)1572864)   // 262144
#define OFF_H1   ((size_t)1835008)   // 1048576
#define OFF_POOL ((size_t)2883584)   // 16384
#define OFF_WC   ((size_t)2899968)   // 5120  folded classifier W [512][10]
#define OFF_BC   ((size_t)2905088)   // 16    folded classifier bias
#define OFF_XB0  ((size_t)2905104)   // 262144 f = 524288 ushort bf16 x
#define OFF_XB   ((size_t)3167248)   // 3145728 f = 6291456 ushort bf16 Xcat [4096][1536max]
#define OFF_WT   ((size_t)6312976)   // 475136 f = 950272 ushort (Wt0,Wt1,Wt2,Wuv)
// total 6788112 floats = 27.2 MB
#define WUV_OFS  933888              // ushort offset of Wuv inside WT region

__device__ __forceinline__ unsigned short f2b(float f) {
    unsigned int x = __float_as_uint(f);
    unsigned int r = x + 0x7FFFu + ((x >> 16) & 1u);
    return (unsigned short)(r >> 16);
}

// ---------------- prep: weight transposes (bf16), Wuv, folded classifier, x->bf16 ----------------
// roles by blockIdx.x:
//  [0,12)    transpose W0 768x64   -> Wt[n*768+k]
//  [12,36)   transpose W1 384x256  -> Wt+49152, ld 384
//  [36,228)  transpose W2 1536x512 -> Wt+147456, ld 1536
//  [228,232) Wuv[n][k] from eW1 (u: rows 0-127, v: rows 128-255)
//  [232,253) Wc = fW1@fW2 (512x10), bc = fb1@fW2 + fb2
//  [253,765) x -> bf16 xb0
__global__ __launch_bounds__(256) void prep_all(const float* __restrict__ W0,
                                                const float* __restrict__ W1,
                                                const float* __restrict__ W2,
                                                const float* __restrict__ eW1,
                                                const float* __restrict__ fW1,
                                                const float* __restrict__ fb1,
                                                const float* __restrict__ fW2,
                                                const float* __restrict__ fb2,
                                                const float* __restrict__ x,
                                                unsigned short* __restrict__ Wt,
                                                float* __restrict__ Wc,
                                                float* __restrict__ bc,
                                                unsigned short* __restrict__ xb0) {
    __shared__ unsigned short Ts[64][65];
    int bid = blockIdx.x, tid = threadIdx.x;
    if (bid < 228) {
        const float* src; unsigned short* dst; int N, ldK, k0, n0;
        if (bid < 12)      { src = W0; dst = Wt;          N = 64;  ldK = 768;  k0 = bid * 64;        n0 = 0; }
        else if (bid < 36) { int t = bid - 12; src = W1; dst = Wt + 49152;  N = 256; ldK = 384;  k0 = (t % 6) * 64;  n0 = (t / 6) * 64; }
        else               { int t = bid - 36; src = W2; dst = Wt + 147456; N = 512; ldK = 1536; k0 = (t % 24) * 64; n0 = (t / 24) * 64; }
#pragma unroll
        for (int p = 0; p < 16; ++p) {
            int e = tid + p * 256; int r = e >> 6, c = e & 63;
            Ts[r][c] = f2b(src[(size_t)(k0 + r) * N + n0 + c]);
        }
        __syncthreads();
#pragma unroll
        for (int p = 0; p < 16; ++p) {
            int e = tid + p * 256; int n = e >> 6, k = e & 63;
            dst[(size_t)(n0 + n) * ldK + k0 + k] = Ts[k][n];
        }
        return;
    }
    if (bid < 232) {
        int tt = bid - 228;
        int half = tt >> 1, kt = tt & 1;        // half: 0=u,1=v ; k block
        int k0 = kt * 64;
        unsigned short* Wuv = Wt + WUV_OFS;
#pragma unroll
        for (int p = 0; p < 16; ++p) {
            int e = tid + p * 256; int r = e >> 6, c = e & 63;
            Ts[r][c] = f2b(eW1[(size_t)(half * 128 + k0 + r) * 64 + c]);
        }
        __syncthreads();
#pragma unroll
        for (int p = 0; p < 16; ++p) {
            int e = tid + p * 256; int n = e >> 6, k = e & 63;
            Wuv[(size_t)(half * 64 + n) * 128 + k0 + k] = Ts[k][n];
        }
        return;
    }
    if (bid < 253) {
        int e = (bid - 232) * 256 + tid;
        if (e < 5120) {
            int i = e / 10, j = e - i * 10;
            float acc = 0.f;
            for (int h = 0; h < 256; ++h) acc += fW1[(size_t)i * 256 + h] * fW2[(size_t)h * 10 + j];
            Wc[e] = acc;
        } else if (e < 5130) {
            int j = e - 5120;
            float acc = fb2[j];
            for (int h = 0; h < 256; ++h) acc += fb1[h] * fW2[(size_t)h * 10 + j];
            bc[j] = acc;
        }
        return;
    }
    {
        int idx = (bid - 253) * 256 + tid;     // 131072 float4s
        float4 vv = ((const float4*)x)[idx];
        ushort4 o;
        o.x = f2b(vv.x); o.y = f2b(vv.y); o.z = f2b(vv.z); o.w = f2b(vv.w);
        ((ushort4*)xb0)[idx] = o;
    }
}

// ---------------- uv = x @ Wuv (+eb1 on u cols) via bf16 MFMA ----------------
__global__ __launch_bounds__(256) void uv_mfma(const unsigned short* __restrict__ xb0,
                                               const unsigned short* __restrict__ Wuv,
                                               const float* __restrict__ eb1,
                                               float* __restrict__ uv) {
    __shared__ __align__(16) unsigned short As[128 * 40];
    __shared__ __align__(16) unsigned short Bs[64 * 40];
    int tid = threadIdx.x;
    int w = tid >> 6, lane = tid & 63, quad = lane >> 4, lr = lane & 15;
    int row0 = blockIdx.y * 128, col0 = blockIdx.x * 64;
    floatx4 acc[2][4];
#pragma unroll
    for (int rt = 0; rt < 2; ++rt)
#pragma unroll
        for (int ct = 0; ct < 4; ++ct) acc[rt][ct] = (floatx4){0.f, 0.f, 0.f, 0.f};
    int arow[2], asub[2];
#pragma unroll
    for (int i = 0; i < 2; ++i) { int ch = tid + i * 256; arow[i] = ch >> 2; asub[i] = ch & 3; }
    int brow = tid >> 2, bsub = tid & 3;
    for (int k0 = 0; k0 < 128; k0 += 32) {
        short8 ra[2];
#pragma unroll
        for (int i = 0; i < 2; ++i)
            ra[i] = *(const short8*)(xb0 + (size_t)(row0 + arow[i]) * 128 + k0 + asub[i] * 8);
        short8 rb = *(const short8*)(Wuv + (size_t)(col0 + brow) * 128 + k0 + bsub * 8);
        __syncthreads();
#pragma unroll
        for (int i = 0; i < 2; ++i) *(short8*)&As[arow[i] * 40 + asub[i] * 8] = ra[i];
        *(short8*)&Bs[brow * 40 + bsub * 8] = rb;
        __syncthreads();
        short8 a[2], b[4];
#pragma unroll
        for (int rt = 0; rt < 2; ++rt)
            a[rt] = *(const short8*)&As[(w * 32 + rt * 16 + lr) * 40 + quad * 8];
#pragma unroll
        for (int ct = 0; ct < 4; ++ct)
            b[ct] = *(const short8*)&Bs[(ct * 16 + lr) * 40 + quad * 8];
#pragma unroll
        for (int rt = 0; rt < 2; ++rt)
#pragma unroll
            for (int ct = 0; ct < 4; ++ct)
                acc[rt][ct] = __builtin_amdgcn_mfma_f32_16x16x32_bf16(a[rt], b[ct], acc[rt][ct], 0, 0, 0);
    }
#pragma unroll
    for (int rt = 0; rt < 2; ++rt) {
        int rbase = row0 + w * 32 + rt * 16 + quad * 4;
#pragma unroll
        for (int ct = 0; ct < 4; ++ct) {
            int col = col0 + ct * 16 + lr;
            float bi = (col < 64) ? eb1[col] : 0.f;
#pragma unroll
            for (int reg = 0; reg < 4; ++reg)
                uv[(size_t)(rbase + reg) * 128 + col] = acc[rt][ct][reg] + bi;
        }
    }
}

// ---------------- edge scores s[b,i,j] (float4 LDS) ----------------
__global__ __launch_bounds__(256) void edge_score(const float* __restrict__ uv,
                                                  const float* __restrict__ eW2,
                                                  const float* __restrict__ eb2,
                                                  float* __restrict__ s) {
    __shared__ __align__(16) float us[16][76];
    __shared__ __align__(16) float vs[16][76];
    __shared__ __align__(16) float w2[64];
    int b = blockIdx.z;
    int i0 = blockIdx.y * 16, j0 = blockIdx.x * 16;
    int tid = threadIdx.x;
    int r = tid >> 4, c4 = (tid & 15) * 4;
    *(float4*)&us[r][c4] = *(const float4*)(uv + ((size_t)(b * Nn + i0 + r)) * 128 + c4);
    *(float4*)&vs[r][c4] = *(const float4*)(uv + ((size_t)(b * Nn + j0 + r)) * 128 + 64 + c4);
    if (tid < 64) w2[tid] = eW2[tid];
    __syncthreads();
    int il = tid >> 4, jl = tid & 15;
    float acc = 0.f;
#pragma unroll
    for (int h4 = 0; h4 < 16; ++h4) {
        float4 uu = *(const float4*)&us[il][h4 * 4];
        float4 vv = *(const float4*)&vs[jl][h4 * 4];
        float4 ww = *(const float4*)&w2[h4 * 4];
        acc += fmaxf(uu.x + vv.x, 0.f) * ww.x + fmaxf(uu.y + vv.y, 0.f) * ww.y
             + fmaxf(uu.z + vv.z, 0.f) * ww.z + fmaxf(uu.w + vv.w, 0.f) * ww.w;
    }
    s[((size_t)(b * Nn + i0 + il)) * Nn + j0 + jl] = acc + eb2[0];
}

// ---------------- fused: A_pred + rowsum + An + degrees + L(An) bf16 ----------------
__global__ __launch_bounds__(256) void edge_apanL(const float* __restrict__ s,
                                                  const float* __restrict__ mask,
                                                  unsigned short* __restrict__ Lb) {
    __shared__ float apS[128][129];
    __shared__ float msk[128], invS[128], t1S[128], Dv[128];
    int b = blockIdx.x, tid = threadIdx.x;
    const float* sb = s + (size_t)b * Nn * Nn;
    if (tid < 128) msk[tid] = mask[b * Nn + tid];
    __syncthreads();
    for (int k = 0; k < 64; ++k) {
        int idx = tid + k * 256;
        int i = idx >> 7, j = idx & 127;
        float val = 0.f;
        if (j > i && msk[i] != 0.f && msk[j] != 0.f)
            val = expf(fminf(0.5f * (sb[idx] + sb[j * Nn + i]), 80.f));
        apS[i][j] = val;
    }
    __syncthreads();
    if (tid < 128) {
        float r = 0.f;
        for (int j = 0; j < 128; ++j) r += apS[tid][j];
        invS[tid] = (r == 0.f) ? 1.f : (1.f / r);
        t1S[tid] = (r == 0.f) ? 0.f : 1.f;
    }
    __syncthreads();
    if (tid < 128) {
        float cw = 0.f;
        for (int j = 0; j < 128; ++j) cw += apS[j][tid] * invS[j];
        Dv[tid] = rsqrtf(t1S[tid] + cw + 1e-5f);   // An symmetric: rowsum == colsum
    }
    __syncthreads();
    unsigned short* Lo = Lb + ((size_t)(Bk + b)) * Nn * Nn;   // rel = 1
    for (int k = 0; k < 64; ++k) {
        int idx = tid + k * 256;
        int i = idx >> 7, j = idx & 127;
        float an = apS[i][j] * invS[i] + apS[j][i] * invS[j];
        Lo[idx] = f2b(Dv[i] * an * Dv[j]);
    }
}

// ---------------- L from input A (rel=0), bf16 ----------------
__global__ __launch_bounds__(256) void buildLb_A(const float* __restrict__ A,
                                                 unsigned short* __restrict__ Lb) {
    int b = blockIdx.x;
    const float* Ar = A + (size_t)b * Nn * Nn;
    __shared__ float part[256];
    __shared__ float Ds[128];
    int tid = threadIdx.x;
    int j = tid & 127, half = tid >> 7;
    float sum = 0.f;
    for (int i = half * 64; i < half * 64 + 64; ++i) sum += Ar[i * Nn + j];
    part[tid] = sum;
    __syncthreads();
    if (tid < 128) Ds[tid] = rsqrtf(part[tid] + part[tid + 128] + 1e-5f);
    __syncthreads();
    unsigned short* Lo = Lb + (size_t)b * Nn * Nn;
    for (int k = 0; k < 64; ++k) {
        int idx = tid + k * 256;
        int i = idx >> 7, jj = idx & 127;
        Lo[idx] = f2b(Ds[i] * Ar[idx] * Ds[jj]);
    }
}

// ---------------- fused Chebyshev staging (per layer) ----------------
template <int FIN>
__global__ __launch_bounds__(256) void cheb_fused(const unsigned short* __restrict__ Lb,
                                                  const float* __restrict__ xin,
                                                  unsigned short* __restrict__ Xb) {
    constexpr int LDK = 136;
    __shared__ __align__(16) unsigned short Ls[128 * LDK];
    __shared__ __align__(16) unsigned short XsT[64 * LDK];
    __shared__ __align__(16) unsigned short T1T[64 * LDK];
    int z = blockIdx.y;
    int b = z & 31, rel = z >> 5;
    int c0 = blockIdx.x * 64;
    int tid = threadIdx.x;
    int w = tid >> 6, lane = tid & 63, quad = lane >> 4, lr = lane & 15;
    const unsigned short* Lp = Lb + ((size_t)(rel * Bk + b)) * Nn * Nn;
    const float* Xp = xin + (size_t)b * Nn * FIN;
    const int ld6 = 6 * FIN;
    unsigned short* Xo = Xb + (size_t)b * Nn * ld6 + rel * 3 * FIN;

#pragma unroll
    for (int i = 0; i < 16; ++i) {
        int idx = tid + i * 256;
        int row = idx >> 5, col4 = (idx & 31) << 2;
        ushort4 val = *(const ushort4*)(Lp + row * Nn + col4);
        *(ushort4*)&Ls[row * LDK + col4] = val;
    }
    {
        int node = tid >> 1, cb = (tid & 1) * 32;
        const float* xr = Xp + (size_t)node * FIN + c0 + cb;
        unsigned short* t0w = Xo + (size_t)node * ld6 + c0 + cb;
#pragma unroll
        for (int i = 0; i < 8; ++i) {
            float4 vv = *(const float4*)(xr + i * 4);
            ushort4 o;
            o.x = f2b(vv.x); o.y = f2b(vv.y); o.z = f2b(vv.z); o.w = f2b(vv.w);
            *(ushort4*)(t0w + i * 4) = o;
            XsT[(cb + i * 4 + 0) * LDK + node] = o.x;
            XsT[(cb + i * 4 + 1) * LDK + node] = o.y;
            XsT[(cb + i * 4 + 2) * LDK + node] = o.z;
            XsT[(cb + i * 4 + 3) * LDK + node] = o.w;
        }
    }
    __syncthreads();

    floatx4 acc[2][4];
#pragma unroll
    for (int rt = 0; rt < 2; ++rt)
#pragma unroll
        for (int ct = 0; ct < 4; ++ct) acc[rt][ct] = (floatx4){0.f, 0.f, 0.f, 0.f};
#pragma unroll
    for (int kc = 0; kc < 4; ++kc) {
        short8 a[2], bb[4];
#pragma unroll
        for (int rt = 0; rt < 2; ++rt)
            a[rt] = *(const short8*)&Ls[((w * 2 + rt) * 16 + lr) * LDK + kc * 32 + quad * 8];
#pragma unroll
        for (int ct = 0; ct < 4; ++ct)
            bb[ct] = *(const short8*)&XsT[(ct * 16 + lr) * LDK + kc * 32 + quad * 8];
#pragma unroll
        for (int rt = 0; rt < 2; ++rt)
#pragma unroll
            for (int ct = 0; ct < 4; ++ct)
                acc[rt][ct] = __builtin_amdgcn_mfma_f32_16x16x32_bf16(a[rt], bb[ct], acc[rt][ct], 0, 0, 0);
    }
#pragma unroll
    for (int rt = 0; rt < 2; ++rt) {
        int rb = (w * 2 + rt) * 16 + quad * 4;
#pragma unroll
        for (int ct = 0; ct < 4; ++ct) {
            int col = ct * 16 + lr;
            ushort4 o;
            o.x = f2b(acc[rt][ct][0]); o.y = f2b(acc[rt][ct][1]);
            o.z = f2b(acc[rt][ct][2]); o.w = f2b(acc[rt][ct][3]);
            *(ushort4*)&T1T[col * LDK + rb] = o;
        }
    }
    __syncthreads();
    {
        int node = tid >> 1, cb = (tid & 1) * 32;
        unsigned short* t1w = Xo + (size_t)node * ld6 + FIN + c0 + cb;
#pragma unroll
        for (int i = 0; i < 8; ++i) {
            ushort4 o;
            o.x = T1T[(cb + i * 4 + 0) * LDK + node];
            o.y = T1T[(cb + i * 4 + 1) * LDK + node];
            o.z = T1T[(cb + i * 4 + 2) * LDK + node];
            o.w = T1T[(cb + i * 4 + 3) * LDK + node];
            *(ushort4*)(t1w + i * 4) = o;
        }
    }
    floatx4 acc2[2][4];
#pragma unroll
    for (int rt = 0; rt < 2; ++rt)
#pragma unroll
        for (int ct = 0; ct < 4; ++ct) acc2[rt][ct] = (floatx4){0.f, 0.f, 0.f, 0.f};
#pragma unroll
    for (int kc = 0; kc < 4; ++kc) {
        short8 a[2], bb[4];
#pragma unroll
        for (int rt = 0; rt < 2; ++rt)
            a[rt] = *(const short8*)&Ls[((w * 2 + rt) * 16 + lr) * LDK + kc * 32 + quad * 8];
#pragma unroll
        for (int ct = 0; ct < 4; ++ct)
            bb[ct] = *(const short8*)&T1T[(ct * 16 + lr) * LDK + kc * 32 + quad * 8];
#pragma unroll
        for (int rt = 0; rt < 2; ++rt)
#pragma unroll
            for (int ct = 0; ct < 4; ++ct)
                acc2[rt][ct] = __builtin_amdgcn_mfma_f32_16x16x32_bf16(a[rt], bb[ct], acc2[rt][ct], 0, 0, 0);
    }
#pragma unroll
    for (int rt = 0; rt < 2; ++rt) {
        int rb = (w * 2 + rt) * 16 + quad * 4;
#pragma unroll
        for (int ct = 0; ct < 4; ++ct) {
            int col = ct * 16 + lr;
            ushort4 o;
            float t0a = Xp[(size_t)(rb + 0) * FIN + c0 + col];
            float t0b = Xp[(size_t)(rb + 1) * FIN + c0 + col];
            float t0c = Xp[(size_t)(rb + 2) * FIN + c0 + col];
            float t0d = Xp[(size_t)(rb + 3) * FIN + c0 + col];
            o.x = f2b(2.f * acc2[rt][ct][0] - t0a);
            o.y = f2b(2.f * acc2[rt][ct][1] - t0b);
            o.z = f2b(2.f * acc2[rt][ct][2] - t0c);
            o.w = f2b(2.f * acc2[rt][ct][3] - t0d);
            *(ushort4*)&XsT[col * LDK + rb] = o;
        }
    }
    __syncthreads();
    {
        int node = tid >> 1, cb = (tid & 1) * 32;
        unsigned short* t2w = Xo + (size_t)node * ld6 + 2 * FIN + c0 + cb;
#pragma unroll
        for (int i = 0; i < 8; ++i) {
            ushort4 o;
            o.x = XsT[(cb + i * 4 + 0) * LDK + node];
            o.y = XsT[(cb + i * 4 + 1) * LDK + node];
            o.z = XsT[(cb + i * 4 + 2) * LDK + node];
            o.w = XsT[(cb + i * 4 + 3) * LDK + node];
            *(ushort4*)(t2w + i * 4) = o;
        }
    }
}

// ---------------- fc via bf16 MFMA + fused bias/mask/BN/relu (+optional max-pool) ----------------
template <int RT, bool POOL>
__global__ __launch_bounds__(256) void fc_mfma(const unsigned short* __restrict__ Xb,
                                               const unsigned short* __restrict__ Wt,
                                               const float* __restrict__ bias,
                                               const float* __restrict__ mask,
                                               const float* __restrict__ bnG,
                                               const float* __restrict__ bnB,
                                               const float* __restrict__ bnM,
                                               const float* __restrict__ bnV,
                                               float* __restrict__ out,
                                               float* __restrict__ pooled,
                                               int Kd, int F) {
    __shared__ __align__(16) unsigned short As[RT * 64 * 40];
    __shared__ __align__(16) unsigned short Bs[64 * 40];
    __shared__ float wmax[4][64];
    int tid = threadIdx.x;
    int w = tid >> 6, lane = tid & 63, quad = lane >> 4, lr = lane & 15;
    int row0 = blockIdx.y * (RT * 64), col0 = blockIdx.x * 64;

    floatx4 acc[RT][4];
#pragma unroll
    for (int rt = 0; rt < RT; ++rt)
#pragma unroll
        for (int ct = 0; ct < 4; ++ct) acc[rt][ct] = (floatx4){0.f, 0.f, 0.f, 0.f};

    int arow[RT], asub[RT];
#pragma unroll
    for (int i = 0; i < RT; ++i) { int ch = tid + i * 256; arow[i] = ch >> 2; asub[i] = ch & 3; }
    int brow = tid >> 2, bsub = tid & 3;

    for (int k0 = 0; k0 < Kd; k0 += 32) {
        short8 ra[RT];
#pragma unroll
        for (int i = 0; i < RT; ++i)
            ra[i] = *(const short8*)(Xb + (size_t)(row0 + arow[i]) * Kd + k0 + asub[i] * 8);
        short8 rb = *(const short8*)(Wt + (size_t)(col0 + brow) * Kd + k0 + bsub * 8);
        __syncthreads();
#pragma unroll
        for (int i = 0; i < RT; ++i)
            *(short8*)&As[arow[i] * 40 + asub[i] * 8] = ra[i];
        *(short8*)&Bs[brow * 40 + bsub * 8] = rb;
        __syncthreads();
        short8 a[RT], b[4];
#pragma unroll
        for (int rt = 0; rt < RT; ++rt)
            a[rt] = *(const short8*)&As[(w * RT * 16 + rt * 16 + lr) * 40 + quad * 8];
#pragma unroll
        for (int ct = 0; ct < 4; ++ct)
            b[ct] = *(const short8*)&Bs[(ct * 16 + lr) * 40 + quad * 8];
#pragma unroll
        for (int rt = 0; rt < RT; ++rt)
#pragma unroll
            for (int ct = 0; ct < 4; ++ct)
                acc[rt][ct] = __builtin_amdgcn_mfma_f32_16x16x32_bf16(a[rt], b[ct], acc[rt][ct], 0, 0, 0);
    }

    float cm[4] = {0.f, 0.f, 0.f, 0.f};
#pragma unroll
    for (int rt = 0; rt < RT; ++rt) {
        int rbase = row0 + w * RT * 16 + rt * 16 + quad * 4;
#pragma unroll
        for (int ct = 0; ct < 4; ++ct) {
            int col = col0 + ct * 16 + lr;
            float bi = bias[col];
            float sc = rsqrtf(bnV[col] + BN_EPS) * bnG[col];
            float bm = bnM[col], bb = bnB[col];
#pragma unroll
            for (int reg = 0; reg < 4; ++reg) {
                int row = rbase + reg;
                float h = acc[rt][ct][reg] + bi;
                h *= mask[row];
                h = (h - bm) * sc + bb;
                h = fmaxf(h, 0.f);
                if (POOL) cm[ct] = fmaxf(cm[ct], h);
                else      out[(size_t)row * F + col] = h;
            }
        }
    }
    if (POOL) {
        // reduce over quad (lanes sharing a col within the wave), then across waves
#pragma unroll
        for (int ct = 0; ct < 4; ++ct) {
            cm[ct] = fmaxf(cm[ct], __shfl_xor(cm[ct], 16));
            cm[ct] = fmaxf(cm[ct], __shfl_xor(cm[ct], 32));
            if (quad == 0) wmax[w][ct * 16 + lr] = cm[ct];
        }
        __syncthreads();
        if (tid < 64) {
            float g = fmaxf(fmaxf(wmax[0][tid], wmax[1][tid]), fmaxf(wmax[2][tid], wmax[3][tid]));
            int b = blockIdx.y;            // RT=2 -> 128 rows/block = one batch
            pooled[(size_t)b * 512 + col0 + tid] = g;
        }
    }
}

// ---------------- final: out = pooled @ Wc + bc ----------------
__global__ __launch_bounds__(256) void cls_final(const float* __restrict__ pooled,
                                                 const float* __restrict__ Wc,
                                                 const float* __restrict__ bc,
                                                 float* __restrict__ out) {
    __shared__ float red[16][17];
    int b = blockIdx.x, tid = threadIdx.x;
    int o = tid & 15, slice = tid >> 4;
    float p = 0.f;
    if (o < 10) {
        for (int kk = 0; kk < 32; ++kk) {
            int k = slice * 32 + kk;
            p += pooled[(size_t)b * 512 + k] * Wc[(size_t)k * 10 + o];
        }
    }
    red[slice][o] = p;
    __syncthreads();
    if (tid < 10) {
        float sum = bc[tid];
        for (int sli = 0; sli < 16; ++sli) sum += red[sli][tid];
        out[(size_t)b * 10 + tid] = sum;
    }
}

extern "C" void kernel_launch(void* const* d_in, const int* in_sizes, int n_in,
                              void* d_out, int out_size, void* d_ws, size_t ws_size,
                              hipStream_t stream) {
    const float* x    = (const float*)d_in[0];
    const float* Ain  = (const float*)d_in[1];
    const float* mask = (const float*)d_in[2];
    const float* eW1  = (const float*)d_in[3];
    const float* eb1  = (const float*)d_in[4];
    const float* eW2  = (const float*)d_in[5];
    const float* eb2  = (const float*)d_in[6];
    const float* fW1  = (const float*)d_in[25];
    const float* fb1  = (const float*)d_in[26];
    const float* fW2  = (const float*)d_in[27];
    const float* fb2  = (const float*)d_in[28];

    float* ws = (float*)d_ws;
    float* uv = ws + OFF_UV;
    float* s  = ws + OFF_S;
    unsigned short* Lb = (unsigned short*)(ws + OFF_LB);
    float* h0 = ws + OFF_H0;
    float* h1 = ws + OFF_H1;
    float* pl = ws + OFF_POOL;
    float* Wc = ws + OFF_WC;
    float* bc = ws + OFF_BC;
    unsigned short* xb0 = (unsigned short*)(ws + OFF_XB0);
    unsigned short* Xb  = (unsigned short*)(ws + OFF_XB);
    unsigned short* Wt  = (unsigned short*)(ws + OFF_WT);

    prep_all<<<765, 256, 0, stream>>>((const float*)d_in[7], (const float*)d_in[13],
                                      (const float*)d_in[19], eW1, fW1, fb1, fW2, fb2, x,
                                      Wt, Wc, bc, xb0);

    uv_mfma<<<dim3(2, 32), 256, 0, stream>>>(xb0, Wt + WUV_OFS, eb1, uv);
    edge_score<<<dim3(8, 8, Bk), 256, 0, stream>>>(uv, eW2, eb2, s);
    edge_apanL<<<Bk, 256, 0, stream>>>(s, mask, Lb);
    buildLb_A<<<Bk, 256, 0, stream>>>(Ain, Lb);

    const float* xins[3] = {x, h0, h1};
    const unsigned short* Wts[3] = {Wt, Wt + 49152, Wt + 147456};
    const int Kds[3] = {768, 384, 1536};
    for (int li = 0; li < 3; ++li) {
        int base = 7 + li * 6;
        const float* gb = (const float*)d_in[base + 1];
        const float* gg = (const float*)d_in[base + 2];
        const float* gB = (const float*)d_in[base + 3];
        const float* gm = (const float*)d_in[base + 4];
        const float* gv = (const float*)d_in[base + 5];

        if (li == 0)      cheb_fused<128><<<dim3(2, 64), 256, 0, stream>>>(Lb, xins[li], Xb);
        else if (li == 1) cheb_fused<64><<<dim3(1, 64), 256, 0, stream>>>(Lb, xins[li], Xb);
        else              cheb_fused<256><<<dim3(4, 64), 256, 0, stream>>>(Lb, xins[li], Xb);

        if (li == 0)
            fc_mfma<1, false><<<dim3(1, 64), 256, 0, stream>>>(
                Xb, Wts[li], gb, mask, gg, gB, gm, gv, h0, nullptr, Kds[li], 64);
        else if (li == 1)
            fc_mfma<2, false><<<dim3(4, 32), 256, 0, stream>>>(
                Xb, Wts[li], gb, mask, gg, gB, gm, gv, h1, nullptr, Kds[li], 256);
        else
            fc_mfma<2, true><<<dim3(8, 32), 256, 0, stream>>>(
                Xb, Wts[li], gb, mask, gg, gB, gm, gv, nullptr, pl, Kds[li], 512);
    }

    cls_final<<<Bk, 256, 0, stream>>>(pl, Wc, bc, (float*)d_out);
}

// Round 6
// 231.210 us; speedup vs baseline: 1.9452x; 1.1641x over previous
//
#include <hip/hip_runtime.h>

// ---------------- constants ----------------
#define Bk 32      // batch
#define Nn 128     // nodes
#define Cc 128     // in channels
#define HE 64      // edge hidden
#define BN_EPS 1e-5f

typedef __attribute__((ext_vector_type(8))) short short8;
typedef __attribute__((ext_vector_type(4))) float floatx4;

// workspace offsets (floats)
#define OFF_UV   ((size_t)0)         // 524288  uv f32 [4096][128] (u cols 0-63, v cols 64-127)
#define OFF_AP   ((size_t)524288)    // 524288  masked exp scores (upper-tri valid)
#define OFF_LB   ((size_t)1048576)   // 524288 f = 1048576 ushort bf16 L [2 rel][32 b][128][128]
#define OFF_H0   ((size_t)1572864)   // 262144
#define OFF_H1   ((size_t)1835008)   // 1048576
#define OFF_POOL ((size_t)2883584)   // 16384
#define OFF_WC   ((size_t)2899968)   // 5120  folded classifier W [512][10]
#define OFF_BC   ((size_t)2905088)   // 16    folded classifier bias
#define OFF_XB0  ((size_t)2905104)   // 262144 f = 524288 ushort bf16 x
#define OFF_XB   ((size_t)3167248)   // 3145728 f = 6291456 ushort bf16 Xcat [4096][1536max]
#define OFF_WT   ((size_t)6312976)   // 475136 f = 950272 ushort (Wt0,Wt1,Wt2,Wuv)
#define WUV_OFS  933888              // ushort offset of Wuv inside WT region

__device__ __forceinline__ unsigned short f2b(float f) {
    unsigned int x = __float_as_uint(f);
    unsigned int r = x + 0x7FFFu + ((x >> 16) & 1u);
    return (unsigned short)(r >> 16);
}

// ---------------- prep: weight transposes (bf16), Wuv, folded classifier, x->bf16 ----------------
__global__ __launch_bounds__(256) void prep_all(const float* __restrict__ W0,
                                                const float* __restrict__ W1,
                                                const float* __restrict__ W2,
                                                const float* __restrict__ eW1,
                                                const float* __restrict__ fW1,
                                                const float* __restrict__ fb1,
                                                const float* __restrict__ fW2,
                                                const float* __restrict__ fb2,
                                                const float* __restrict__ x,
                                                unsigned short* __restrict__ Wt,
                                                float* __restrict__ Wc,
                                                float* __restrict__ bc,
                                                unsigned short* __restrict__ xb0) {
    __shared__ unsigned short Ts[64][65];
    int bid = blockIdx.x, tid = threadIdx.x;
    if (bid < 228) {
        const float* src; unsigned short* dst; int N, ldK, k0, n0;
        if (bid < 12)      { src = W0; dst = Wt;          N = 64;  ldK = 768;  k0 = bid * 64;        n0 = 0; }
        else if (bid < 36) { int t = bid - 12; src = W1; dst = Wt + 49152;  N = 256; ldK = 384;  k0 = (t % 6) * 64;  n0 = (t / 6) * 64; }
        else               { int t = bid - 36; src = W2; dst = Wt + 147456; N = 512; ldK = 1536; k0 = (t % 24) * 64; n0 = (t / 24) * 64; }
#pragma unroll
        for (int p = 0; p < 16; ++p) {
            int e = tid + p * 256; int r = e >> 6, c = e & 63;
            Ts[r][c] = f2b(src[(size_t)(k0 + r) * N + n0 + c]);
        }
        __syncthreads();
#pragma unroll
        for (int p = 0; p < 16; ++p) {
            int e = tid + p * 256; int n = e >> 6, k = e & 63;
            dst[(size_t)(n0 + n) * ldK + k0 + k] = Ts[k][n];
        }
        return;
    }
    if (bid < 232) {
        int tt = bid - 228;
        int half = tt >> 1, kt = tt & 1;
        int k0 = kt * 64;
        unsigned short* Wuv = Wt + WUV_OFS;
#pragma unroll
        for (int p = 0; p < 16; ++p) {
            int e = tid + p * 256; int r = e >> 6, c = e & 63;
            Ts[r][c] = f2b(eW1[(size_t)(half * 128 + k0 + r) * 64 + c]);
        }
        __syncthreads();
#pragma unroll
        for (int p = 0; p < 16; ++p) {
            int e = tid + p * 256; int n = e >> 6, k = e & 63;
            Wuv[(size_t)(half * 64 + n) * 128 + k0 + k] = Ts[k][n];
        }
        return;
    }
    if (bid < 253) {
        int e = (bid - 232) * 256 + tid;
        if (e < 5120) {
            int i = e / 10, j = e - i * 10;
            float acc = 0.f;
            for (int h = 0; h < 256; ++h) acc += fW1[(size_t)i * 256 + h] * fW2[(size_t)h * 10 + j];
            Wc[e] = acc;
        } else if (e < 5130) {
            int j = e - 5120;
            float acc = fb2[j];
            for (int h = 0; h < 256; ++h) acc += fb1[h] * fW2[(size_t)h * 10 + j];
            bc[j] = acc;
        }
        return;
    }
    {
        int idx = (bid - 253) * 256 + tid;
        float4 vv = ((const float4*)x)[idx];
        ushort4 o;
        o.x = f2b(vv.x); o.y = f2b(vv.y); o.z = f2b(vv.z); o.w = f2b(vv.w);
        ((ushort4*)xb0)[idx] = o;
    }
}

// ---------------- uv = x @ Wuv (+eb1 on u cols) via bf16 MFMA ----------------
__global__ __launch_bounds__(256) void uv_mfma(const unsigned short* __restrict__ xb0,
                                               const unsigned short* __restrict__ Wuv,
                                               const float* __restrict__ eb1,
                                               float* __restrict__ uv) {
    __shared__ __align__(16) unsigned short As[128 * 40];
    __shared__ __align__(16) unsigned short Bs[64 * 40];
    int tid = threadIdx.x;
    int w = tid >> 6, lane = tid & 63, quad = lane >> 4, lr = lane & 15;
    int row0 = blockIdx.y * 128, col0 = blockIdx.x * 64;
    floatx4 acc[2][4];
#pragma unroll
    for (int rt = 0; rt < 2; ++rt)
#pragma unroll
        for (int ct = 0; ct < 4; ++ct) acc[rt][ct] = (floatx4){0.f, 0.f, 0.f, 0.f};
    int arow[2], asub[2];
#pragma unroll
    for (int i = 0; i < 2; ++i) { int ch = tid + i * 256; arow[i] = ch >> 2; asub[i] = ch & 3; }
    int brow = tid >> 2, bsub = tid & 3;
    for (int k0 = 0; k0 < 128; k0 += 32) {
        short8 ra[2];
#pragma unroll
        for (int i = 0; i < 2; ++i)
            ra[i] = *(const short8*)(xb0 + (size_t)(row0 + arow[i]) * 128 + k0 + asub[i] * 8);
        short8 rb = *(const short8*)(Wuv + (size_t)(col0 + brow) * 128 + k0 + bsub * 8);
        __syncthreads();
#pragma unroll
        for (int i = 0; i < 2; ++i) *(short8*)&As[arow[i] * 40 + asub[i] * 8] = ra[i];
        *(short8*)&Bs[brow * 40 + bsub * 8] = rb;
        __syncthreads();
        short8 a[2], b[4];
#pragma unroll
        for (int rt = 0; rt < 2; ++rt)
            a[rt] = *(const short8*)&As[(w * 32 + rt * 16 + lr) * 40 + quad * 8];
#pragma unroll
        for (int ct = 0; ct < 4; ++ct)
            b[ct] = *(const short8*)&Bs[(ct * 16 + lr) * 40 + quad * 8];
#pragma unroll
        for (int rt = 0; rt < 2; ++rt)
#pragma unroll
            for (int ct = 0; ct < 4; ++ct)
                acc[rt][ct] = __builtin_amdgcn_mfma_f32_16x16x32_bf16(a[rt], b[ct], acc[rt][ct], 0, 0, 0);
    }
#pragma unroll
    for (int rt = 0; rt < 2; ++rt) {
        int rbase = row0 + w * 32 + rt * 16 + quad * 4;
#pragma unroll
        for (int ct = 0; ct < 4; ++ct) {
            int col = col0 + ct * 16 + lr;
            float bi = (col < 64) ? eb1[col] : 0.f;
#pragma unroll
            for (int reg = 0; reg < 4; ++reg)
                uv[(size_t)(rbase + reg) * 128 + col] = acc[rt][ct][reg] + bi;
        }
    }
}

// ---------------- symmetric masked-exp edge scores (upper-tri tile pairs only) ----------------
// ap[b,i,j] = mask_i*mask_j * exp(min(0.5*(s_ij+s_ji)+eb2, 80)) for j>i; j<=i left unwritten.
__global__ __launch_bounds__(256) void edge_sym(const float* __restrict__ uv,
                                                const float* __restrict__ eW2,
                                                const float* __restrict__ eb2,
                                                const float* __restrict__ mask,
                                                float* __restrict__ ap) {
    __shared__ __align__(16) float ui[16][68], vi[16][68], uj[16][68], vj[16][68];
    __shared__ __align__(16) float w2[64];
    int t = blockIdx.x, b = blockIdx.y;
    int ti = 0, rem = t;
    for (;;) { int w = 8 - ti; if (rem < w) break; rem -= w; ++ti; }
    int tj = ti + rem;
    int i0 = ti * 16, j0 = tj * 16;
    int tid = threadIdx.x;
    int r = tid >> 4, c4 = (tid & 15) * 4;
    const float* uvb = uv + (size_t)b * Nn * 128;
    *(float4*)&ui[r][c4] = *(const float4*)(uvb + (size_t)(i0 + r) * 128 + c4);
    *(float4*)&vi[r][c4] = *(const float4*)(uvb + (size_t)(i0 + r) * 128 + 64 + c4);
    *(float4*)&uj[r][c4] = *(const float4*)(uvb + (size_t)(j0 + r) * 128 + c4);
    *(float4*)&vj[r][c4] = *(const float4*)(uvb + (size_t)(j0 + r) * 128 + 64 + c4);
    if (tid < 64) w2[tid] = eW2[tid];
    __syncthreads();
    int il = tid >> 4, jl = tid & 15;
    int gi = i0 + il, gj = j0 + jl;
    if (gj <= gi) return;
    float d = 0.f;
#pragma unroll
    for (int h4 = 0; h4 < 16; ++h4) {
        float4 a1 = *(const float4*)&ui[il][h4 * 4];
        float4 b1 = *(const float4*)&vj[jl][h4 * 4];
        float4 a2 = *(const float4*)&uj[jl][h4 * 4];
        float4 b2 = *(const float4*)&vi[il][h4 * 4];
        float4 ww = *(const float4*)&w2[h4 * 4];
        d += (fmaxf(a1.x + b1.x, 0.f) + fmaxf(a2.x + b2.x, 0.f)) * ww.x
           + (fmaxf(a1.y + b1.y, 0.f) + fmaxf(a2.y + b2.y, 0.f)) * ww.y
           + (fmaxf(a1.z + b1.z, 0.f) + fmaxf(a2.z + b2.z, 0.f)) * ww.z
           + (fmaxf(a1.w + b1.w, 0.f) + fmaxf(a2.w + b2.w, 0.f)) * ww.w;
    }
    float p = 0.5f * d + eb2[0];
    float mi = mask[b * Nn + gi], mj = mask[b * Nn + gj];
    float val = (mi != 0.f && mj != 0.f) ? expf(fminf(p, 80.f)) : 0.f;
    ap[((size_t)(b * Nn + gi)) * Nn + gj] = val;
}

// ---------------- merged: [0,32) An path -> L(rel1); [32,64) A path -> L(rel0) ----------------
__global__ __launch_bounds__(256) void adj_L(const float* __restrict__ ap,
                                             const float* __restrict__ A,
                                             unsigned short* __restrict__ Lb) {
    int bid = blockIdx.x, tid = threadIdx.x;
    if (bid < 32) {
        int b = bid;
        __shared__ float apS[128][129];
        __shared__ float part[256], invS[128], t1S[128], Dv[128];
        const float* apg = ap + (size_t)b * Nn * Nn;
        for (int k = 0; k < 64; ++k) {
            int idx = tid + k * 256;
            int i = idx >> 7, j = idx & 127;
            float g = apg[idx];
            apS[i][j] = (j > i) ? g : 0.f;
        }
        __syncthreads();
        {
            int row = tid >> 1, half = tid & 1;
            float s0 = 0.f;
            for (int j = half * 64; j < half * 64 + 64; ++j) s0 += apS[row][j];
            part[tid] = s0;
        }
        __syncthreads();
        if (tid < 128) {
            float rsum = part[tid * 2] + part[tid * 2 + 1];
            invS[tid] = (rsum == 0.f) ? 1.f : (1.f / rsum);
            t1S[tid]  = (rsum == 0.f) ? 0.f : 1.f;
        }
        __syncthreads();
        {
            int col = tid >> 1, half = tid & 1;
            float s0 = 0.f;
            for (int j = half * 64; j < half * 64 + 64; ++j) s0 += apS[j][col] * invS[j];
            part[tid] = s0;
        }
        __syncthreads();
        if (tid < 128) Dv[tid] = rsqrtf(t1S[tid] + part[tid * 2] + part[tid * 2 + 1] + 1e-5f);
        __syncthreads();
        unsigned short* Lo = Lb + ((size_t)(Bk + b)) * Nn * Nn;
        for (int k = 0; k < 64; ++k) {
            int idx = tid + k * 256;
            int i = idx >> 7, j = idx & 127;
            float an = apS[i][j] * invS[i] + apS[j][i] * invS[j];
            Lo[idx] = f2b(Dv[i] * an * Dv[j]);
        }
    } else {
        int b = bid - 32;
        const float* Ar = A + (size_t)b * Nn * Nn;
        __shared__ float part2[256];
        __shared__ float Ds[128];
        int j = tid & 127, half = tid >> 7;
        float sum = 0.f;
        for (int i = half * 64; i < half * 64 + 64; ++i) sum += Ar[i * Nn + j];
        part2[tid] = sum;
        __syncthreads();
        if (tid < 128) Ds[tid] = rsqrtf(part2[tid] + part2[tid + 128] + 1e-5f);
        __syncthreads();
        unsigned short* Lo = Lb + (size_t)b * Nn * Nn;
        for (int k = 0; k < 64; ++k) {
            int idx = tid + k * 256;
            int i = idx >> 7, jj = idx & 127;
            Lo[idx] = f2b(Ds[i] * Ar[idx] * Ds[jj]);
        }
    }
}

// ---------------- fused Chebyshev staging (per layer), COLS-wide column tiles ----------------
template <int FIN, int COLS>
__global__ __launch_bounds__(256) void cheb_fused(const unsigned short* __restrict__ Lb,
                                                  const float* __restrict__ xin,
                                                  unsigned short* __restrict__ Xb) {
    constexpr int LDK = 136;
    constexpr int NCT = COLS / 16;
    constexpr int HC  = COLS / 2;
    __shared__ __align__(16) unsigned short Ls[128 * LDK];
    __shared__ __align__(16) unsigned short XsT[COLS * LDK];
    __shared__ __align__(16) unsigned short T1T[COLS * LDK];
    int z = blockIdx.y;
    int b = z & 31, rel = z >> 5;
    int c0 = blockIdx.x * COLS;
    int tid = threadIdx.x;
    int w = tid >> 6, lane = tid & 63, quad = lane >> 4, lr = lane & 15;
    const unsigned short* Lp = Lb + ((size_t)(rel * Bk + b)) * Nn * Nn;
    const float* Xp = xin + (size_t)b * Nn * FIN;
    const int ld6 = 6 * FIN;
    unsigned short* Xo = Xb + (size_t)b * Nn * ld6 + rel * 3 * FIN;

#pragma unroll
    for (int i = 0; i < 16; ++i) {
        int idx = tid + i * 256;
        int row = idx >> 5, col4 = (idx & 31) << 2;
        ushort4 val = *(const ushort4*)(Lp + row * Nn + col4);
        *(ushort4*)&Ls[row * LDK + col4] = val;
    }
    {
        int node = tid >> 1, cb = (tid & 1) * HC;
        const float* xr = Xp + (size_t)node * FIN + c0 + cb;
        unsigned short* t0w = Xo + (size_t)node * ld6 + c0 + cb;
#pragma unroll
        for (int i = 0; i < HC / 4; ++i) {
            float4 vv = *(const float4*)(xr + i * 4);
            ushort4 o;
            o.x = f2b(vv.x); o.y = f2b(vv.y); o.z = f2b(vv.z); o.w = f2b(vv.w);
            *(ushort4*)(t0w + i * 4) = o;
            XsT[(cb + i * 4 + 0) * LDK + node] = o.x;
            XsT[(cb + i * 4 + 1) * LDK + node] = o.y;
            XsT[(cb + i * 4 + 2) * LDK + node] = o.z;
            XsT[(cb + i * 4 + 3) * LDK + node] = o.w;
        }
    }
    __syncthreads();

    floatx4 acc[2][NCT];
#pragma unroll
    for (int rt = 0; rt < 2; ++rt)
#pragma unroll
        for (int ct = 0; ct < NCT; ++ct) acc[rt][ct] = (floatx4){0.f, 0.f, 0.f, 0.f};
#pragma unroll
    for (int kc = 0; kc < 4; ++kc) {
        short8 a[2], bb[NCT];
#pragma unroll
        for (int rt = 0; rt < 2; ++rt)
            a[rt] = *(const short8*)&Ls[((w * 2 + rt) * 16 + lr) * LDK + kc * 32 + quad * 8];
#pragma unroll
        for (int ct = 0; ct < NCT; ++ct)
            bb[ct] = *(const short8*)&XsT[(ct * 16 + lr) * LDK + kc * 32 + quad * 8];
#pragma unroll
        for (int rt = 0; rt < 2; ++rt)
#pragma unroll
            for (int ct = 0; ct < NCT; ++ct)
                acc[rt][ct] = __builtin_amdgcn_mfma_f32_16x16x32_bf16(a[rt], bb[ct], acc[rt][ct], 0, 0, 0);
    }
#pragma unroll
    for (int rt = 0; rt < 2; ++rt) {
        int rb = (w * 2 + rt) * 16 + quad * 4;
#pragma unroll
        for (int ct = 0; ct < NCT; ++ct) {
            int col = ct * 16 + lr;
            ushort4 o;
            o.x = f2b(acc[rt][ct][0]); o.y = f2b(acc[rt][ct][1]);
            o.z = f2b(acc[rt][ct][2]); o.w = f2b(acc[rt][ct][3]);
            *(ushort4*)&T1T[col * LDK + rb] = o;
        }
    }
    __syncthreads();
    {
        int node = tid >> 1, cb = (tid & 1) * HC;
        unsigned short* t1w = Xo + (size_t)node * ld6 + FIN + c0 + cb;
#pragma unroll
        for (int i = 0; i < HC / 4; ++i) {
            ushort4 o;
            o.x = T1T[(cb + i * 4 + 0) * LDK + node];
            o.y = T1T[(cb + i * 4 + 1) * LDK + node];
            o.z = T1T[(cb + i * 4 + 2) * LDK + node];
            o.w = T1T[(cb + i * 4 + 3) * LDK + node];
            *(ushort4*)(t1w + i * 4) = o;
        }
    }
    floatx4 acc2[2][NCT];
#pragma unroll
    for (int rt = 0; rt < 2; ++rt)
#pragma unroll
        for (int ct = 0; ct < NCT; ++ct) acc2[rt][ct] = (floatx4){0.f, 0.f, 0.f, 0.f};
#pragma unroll
    for (int kc = 0; kc < 4; ++kc) {
        short8 a[2], bb[NCT];
#pragma unroll
        for (int rt = 0; rt < 2; ++rt)
            a[rt] = *(const short8*)&Ls[((w * 2 + rt) * 16 + lr) * LDK + kc * 32 + quad * 8];
#pragma unroll
        for (int ct = 0; ct < NCT; ++ct)
            bb[ct] = *(const short8*)&T1T[(ct * 16 + lr) * LDK + kc * 32 + quad * 8];
#pragma unroll
        for (int rt = 0; rt < 2; ++rt)
#pragma unroll
            for (int ct = 0; ct < NCT; ++ct)
                acc2[rt][ct] = __builtin_amdgcn_mfma_f32_16x16x32_bf16(a[rt], bb[ct], acc2[rt][ct], 0, 0, 0);
    }
#pragma unroll
    for (int rt = 0; rt < 2; ++rt) {
        int rb = (w * 2 + rt) * 16 + quad * 4;
#pragma unroll
        for (int ct = 0; ct < NCT; ++ct) {
            int col = ct * 16 + lr;
            ushort4 o;
            float t0a = Xp[(size_t)(rb + 0) * FIN + c0 + col];
            float t0b = Xp[(size_t)(rb + 1) * FIN + c0 + col];
            float t0c = Xp[(size_t)(rb + 2) * FIN + c0 + col];
            float t0d = Xp[(size_t)(rb + 3) * FIN + c0 + col];
            o.x = f2b(2.f * acc2[rt][ct][0] - t0a);
            o.y = f2b(2.f * acc2[rt][ct][1] - t0b);
            o.z = f2b(2.f * acc2[rt][ct][2] - t0c);
            o.w = f2b(2.f * acc2[rt][ct][3] - t0d);
            *(ushort4*)&XsT[col * LDK + rb] = o;
        }
    }
    __syncthreads();
    {
        int node = tid >> 1, cb = (tid & 1) * HC;
        unsigned short* t2w = Xo + (size_t)node * ld6 + 2 * FIN + c0 + cb;
#pragma unroll
        for (int i = 0; i < HC / 4; ++i) {
            ushort4 o;
            o.x = XsT[(cb + i * 4 + 0) * LDK + node];
            o.y = XsT[(cb + i * 4 + 1) * LDK + node];
            o.z = XsT[(cb + i * 4 + 2) * LDK + node];
            o.w = XsT[(cb + i * 4 + 3) * LDK + node];
            *(ushort4*)(t2w + i * 4) = o;
        }
    }
}

// ---------------- fc via bf16 MFMA + fused bias/mask/BN/relu (+optional max-pool) ----------------
template <int RT, bool POOL>
__global__ __launch_bounds__(256) void fc_mfma(const unsigned short* __restrict__ Xb,
                                               const unsigned short* __restrict__ Wt,
                                               const float* __restrict__ bias,
                                               const float* __restrict__ mask,
                                               const float* __restrict__ bnG,
                                               const float* __restrict__ bnB,
                                               const float* __restrict__ bnM,
                                               const float* __restrict__ bnV,
                                               float* __restrict__ out,
                                               float* __restrict__ pooled,
                                               int Kd, int F) {
    __shared__ __align__(16) unsigned short As[RT * 64 * 40];
    __shared__ __align__(16) unsigned short Bs[64 * 40];
    __shared__ float wmax[4][64];
    int tid = threadIdx.x;
    int w = tid >> 6, lane = tid & 63, quad = lane >> 4, lr = lane & 15;
    int row0 = blockIdx.y * (RT * 64), col0 = blockIdx.x * 64;

    floatx4 acc[RT][4];
#pragma unroll
    for (int rt = 0; rt < RT; ++rt)
#pragma unroll
        for (int ct = 0; ct < 4; ++ct) acc[rt][ct] = (floatx4){0.f, 0.f, 0.f, 0.f};

    int arow[RT], asub[RT];
#pragma unroll
    for (int i = 0; i < RT; ++i) { int ch = tid + i * 256; arow[i] = ch >> 2; asub[i] = ch & 3; }
    int brow = tid >> 2, bsub = tid & 3;

    for (int k0 = 0; k0 < Kd; k0 += 32) {
        short8 ra[RT];
#pragma unroll
        for (int i = 0; i < RT; ++i)
            ra[i] = *(const short8*)(Xb + (size_t)(row0 + arow[i]) * Kd + k0 + asub[i] * 8);
        short8 rb = *(const short8*)(Wt + (size_t)(col0 + brow) * Kd + k0 + bsub * 8);
        __syncthreads();
#pragma unroll
        for (int i = 0; i < RT; ++i)
            *(short8*)&As[arow[i] * 40 + asub[i] * 8] = ra[i];
        *(short8*)&Bs[brow * 40 + bsub * 8] = rb;
        __syncthreads();
        short8 a[RT], b[4];
#pragma unroll
        for (int rt = 0; rt < RT; ++rt)
            a[rt] = *(const short8*)&As[(w * RT * 16 + rt * 16 + lr) * 40 + quad * 8];
#pragma unroll
        for (int ct = 0; ct < 4; ++ct)
            b[ct] = *(const short8*)&Bs[(ct * 16 + lr) * 40 + quad * 8];
#pragma unroll
        for (int rt = 0; rt < RT; ++rt)
#pragma unroll
            for (int ct = 0; ct < 4; ++ct)
                acc[rt][ct] = __builtin_amdgcn_mfma_f32_16x16x32_bf16(a[rt], b[ct], acc[rt][ct], 0, 0, 0);
    }

    float cm[4] = {0.f, 0.f, 0.f, 0.f};
#pragma unroll
    for (int rt = 0; rt < RT; ++rt) {
        int rbase = row0 + w * RT * 16 + rt * 16 + quad * 4;
#pragma unroll
        for (int ct = 0; ct < 4; ++ct) {
            int col = col0 + ct * 16 + lr;
            float bi = bias[col];
            float sc = rsqrtf(bnV[col] + BN_EPS) * bnG[col];
            float bm = bnM[col], bb = bnB[col];
#pragma unroll
            for (int reg = 0; reg < 4; ++reg) {
                int row = rbase + reg;
                float h = acc[rt][ct][reg] + bi;
                h *= mask[row];
                h = (h - bm) * sc + bb;
                h = fmaxf(h, 0.f);
                if (POOL) cm[ct] = fmaxf(cm[ct], h);
                else      out[(size_t)row * F + col] = h;
            }
        }
    }
    if (POOL) {
#pragma unroll
        for (int ct = 0; ct < 4; ++ct) {
            cm[ct] = fmaxf(cm[ct], __shfl_xor(cm[ct], 16));
            cm[ct] = fmaxf(cm[ct], __shfl_xor(cm[ct], 32));
            if (quad == 0) wmax[w][ct * 16 + lr] = cm[ct];
        }
        __syncthreads();
        if (tid < 64) {
            float g = fmaxf(fmaxf(wmax[0][tid], wmax[1][tid]), fmaxf(wmax[2][tid], wmax[3][tid]));
            int b = blockIdx.y;
            pooled[(size_t)b * 512 + col0 + tid] = g;
        }
    }
}

// ---------------- final: out = pooled @ Wc + bc ----------------
__global__ __launch_bounds__(256) void cls_final(const float* __restrict__ pooled,
                                                 const float* __restrict__ Wc,
                                                 const float* __restrict__ bc,
                                                 float* __restrict__ out) {
    __shared__ float red[16][17];
    int b = blockIdx.x, tid = threadIdx.x;
    int o = tid & 15, slice = tid >> 4;
    float p = 0.f;
    if (o < 10) {
        for (int kk = 0; kk < 32; ++kk) {
            int k = slice * 32 + kk;
            p += pooled[(size_t)b * 512 + k] * Wc[(size_t)k * 10 + o];
        }
    }
    red[slice][o] = p;
    __syncthreads();
    if (tid < 10) {
        float sum = bc[tid];
        for (int sli = 0; sli < 16; ++sli) sum += red[sli][tid];
        out[(size_t)b * 10 + tid] = sum;
    }
}

extern "C" void kernel_launch(void* const* d_in, const int* in_sizes, int n_in,
                              void* d_out, int out_size, void* d_ws, size_t ws_size,
                              hipStream_t stream) {
    const float* x    = (const float*)d_in[0];
    const float* Ain  = (const float*)d_in[1];
    const float* mask = (const float*)d_in[2];
    const float* eW1  = (const float*)d_in[3];
    const float* eb1  = (const float*)d_in[4];
    const float* eW2  = (const float*)d_in[5];
    const float* eb2  = (const float*)d_in[6];
    const float* fW1  = (const float*)d_in[25];
    const float* fb1  = (const float*)d_in[26];
    const float* fW2  = (const float*)d_in[27];
    const float* fb2  = (const float*)d_in[28];

    float* ws = (float*)d_ws;
    float* uv = ws + OFF_UV;
    float* ap = ws + OFF_AP;
    unsigned short* Lb = (unsigned short*)(ws + OFF_LB);
    float* h0 = ws + OFF_H0;
    float* h1 = ws + OFF_H1;
    float* pl = ws + OFF_POOL;
    float* Wc = ws + OFF_WC;
    float* bc = ws + OFF_BC;
    unsigned short* xb0 = (unsigned short*)(ws + OFF_XB0);
    unsigned short* Xb  = (unsigned short*)(ws + OFF_XB);
    unsigned short* Wt  = (unsigned short*)(ws + OFF_WT);

    prep_all<<<765, 256, 0, stream>>>((const float*)d_in[7], (const float*)d_in[13],
                                      (const float*)d_in[19], eW1, fW1, fb1, fW2, fb2, x,
                                      Wt, Wc, bc, xb0);

    uv_mfma<<<dim3(2, 32), 256, 0, stream>>>(xb0, Wt + WUV_OFS, eb1, uv);
    edge_sym<<<dim3(36, Bk), 256, 0, stream>>>(uv, eW2, eb2, mask, ap);
    adj_L<<<64, 256, 0, stream>>>(ap, Ain, Lb);

    const float* xins[3] = {x, h0, h1};
    const unsigned short* Wts[3] = {Wt, Wt + 49152, Wt + 147456};
    const int Kds[3] = {768, 384, 1536};
    for (int li = 0; li < 3; ++li) {
        int base = 7 + li * 6;
        const float* gb = (const float*)d_in[base + 1];
        const float* gg = (const float*)d_in[base + 2];
        const float* gB = (const float*)d_in[base + 3];
        const float* gm = (const float*)d_in[base + 4];
        const float* gv = (const float*)d_in[base + 5];

        if (li == 0)      cheb_fused<128, 32><<<dim3(4, 64), 256, 0, stream>>>(Lb, xins[li], Xb);
        else if (li == 1) cheb_fused<64, 32><<<dim3(2, 64), 256, 0, stream>>>(Lb, xins[li], Xb);
        else              cheb_fused<256, 32><<<dim3(8, 64), 256, 0, stream>>>(Lb, xins[li], Xb);

        if (li == 0)
            fc_mfma<1, false><<<dim3(1, 64), 256, 0, stream>>>(
                Xb, Wts[li], gb, mask, gg, gB, gm, gv, h0, nullptr, Kds[li], 64);
        else if (li == 1)
            fc_mfma<2, false><<<dim3(4, 32), 256, 0, stream>>>(
                Xb, Wts[li], gb, mask, gg, gB, gm, gv, h1, nullptr, Kds[li], 256);
        else
            fc_mfma<2, true><<<dim3(8, 32), 256, 0, stream>>>(
                Xb, Wts[li], gb, mask, gg, gB, gm, gv, nullptr, pl, Kds[li], 512);
    }

    cls_final<<<Bk, 256, 0, stream>>>(pl, Wc, bc, (float*)d_out);
}